// Round 1
// baseline (2222.895 us; speedup 1.0000x reference)
//
#include <hip/hip_runtime.h>
#include <cstdint>
#include <cstddef>

#define NN 50000
#define EE 800000
#define ET 850000   // EE + NN self loops

// ---------------------------------------------------------------- CSR build
__global__ __launch_bounds__(256) void k_count(const int* __restrict__ edge,
                                               int* __restrict__ counts) {
  int e = blockIdx.x * 256 + threadIdx.x;
  if (e >= ET) return;
  int dd = (e < EE) ? edge[EE + e] : (e - EE);
  atomicAdd(&counts[dd], 1);
}

__global__ __launch_bounds__(1024) void k_scan(const int* __restrict__ counts,
                                               int* __restrict__ row_ptr,
                                               int* __restrict__ cursor) {
  __shared__ int tmp[1024];
  const int CH = (NN + 1023) / 1024;  // 49
  int tid = threadIdx.x;
  int base = tid * CH;
  int sum = 0;
  for (int i = 0; i < CH; ++i) {
    int idx = base + i;
    if (idx < NN) sum += counts[idx];
  }
  tmp[tid] = sum;
  __syncthreads();
  for (int o = 1; o < 1024; o <<= 1) {
    int v = (tid >= o) ? tmp[tid - o] : 0;
    __syncthreads();
    tmp[tid] += v;
    __syncthreads();
  }
  int off = tmp[tid] - sum;  // exclusive prefix
  for (int i = 0; i < CH; ++i) {
    int idx = base + i;
    if (idx < NN) {
      row_ptr[idx] = off;
      cursor[idx] = off;
      off += counts[idx];
    }
  }
  if (tid == 0) row_ptr[NN] = ET;
}

__global__ __launch_bounds__(256) void k_fill(const int* __restrict__ edge,
                                              int* __restrict__ cursor,
                                              int* __restrict__ col_src,
                                              int* __restrict__ eid2pos) {
  int e = blockIdx.x * 256 + threadIdx.x;
  if (e >= ET) return;
  int ss, dd;
  if (e < EE) { ss = edge[e]; dd = edge[EE + e]; }
  else        { ss = dd = e - EE; }
  int pos = atomicAdd(&cursor[dd], 1);
  col_src[pos] = ss;
  eid2pos[e] = pos;
}

// ---------------------------------------------------------------- GEMM f32
// C[M,Nc] = A[M,K] @ B[K,Nc]  (+bias, +relu optional). Nc,K multiples of 16/128.
__global__ __launch_bounds__(256) void k_gemm(const float* __restrict__ A,
                                              const float* __restrict__ B,
                                              float* __restrict__ C,
                                              int M, int K, int Nc,
                                              const float* __restrict__ bias,
                                              int do_relu) {
  __shared__ float As[16][128];
  __shared__ float Bs[16][128];
  int row0 = blockIdx.x * 128;
  int col0 = blockIdx.y * 128;
  int t = threadIdx.x;
  int tx = t & 15, ty = t >> 4;
  float acc[8][8] = {};

  int ar = t >> 2;            // 0..63 (A row within half-tile)
  int ac = (t & 3) * 4;       // 0,4,8,12 (A col)
  int bk = t >> 5;            // 0..7   (B row within half)
  int bc = (t & 31) * 4;      // 0..124 (B col)

  for (int k0 = 0; k0 < K; k0 += 16) {
#pragma unroll
    for (int rep = 0; rep < 2; ++rep) {
      int r2 = ar + rep * 64;
      int grow = row0 + r2;
      float4 v = make_float4(0.f, 0.f, 0.f, 0.f);
      if (grow < M) v = *(const float4*)&A[(size_t)grow * K + k0 + ac];
      As[ac + 0][r2] = v.x; As[ac + 1][r2] = v.y;
      As[ac + 2][r2] = v.z; As[ac + 3][r2] = v.w;
    }
#pragma unroll
    for (int rep = 0; rep < 2; ++rep) {
      int k = bk + rep * 8;
      float4 v = *(const float4*)&B[(size_t)(k0 + k) * Nc + col0 + bc];
      Bs[k][bc + 0] = v.x; Bs[k][bc + 1] = v.y;
      Bs[k][bc + 2] = v.z; Bs[k][bc + 3] = v.w;
    }
    __syncthreads();
#pragma unroll
    for (int k = 0; k < 16; ++k) {
      float a[8], b[8];
#pragma unroll
      for (int i = 0; i < 8; ++i) a[i] = As[k][ty * 8 + i];
#pragma unroll
      for (int j = 0; j < 8; ++j) b[j] = Bs[k][tx * 8 + j];
#pragma unroll
      for (int i = 0; i < 8; ++i)
#pragma unroll
        for (int j = 0; j < 8; ++j) acc[i][j] += a[i] * b[j];
    }
    __syncthreads();
  }

#pragma unroll
  for (int i = 0; i < 8; ++i) {
    int grow = row0 + ty * 8 + i;
    if (grow >= M) continue;
#pragma unroll
    for (int j = 0; j < 8; j += 4) {
      int gcol = col0 + tx * 8 + j;
      float4 v = make_float4(acc[i][j], acc[i][j + 1], acc[i][j + 2], acc[i][j + 3]);
      if (bias) {
        v.x += bias[gcol + 0]; v.y += bias[gcol + 1];
        v.z += bias[gcol + 2]; v.w += bias[gcol + 3];
      }
      if (do_relu) {
        v.x = fmaxf(v.x, 0.f); v.y = fmaxf(v.y, 0.f);
        v.z = fmaxf(v.z, 0.f); v.w = fmaxf(v.w, 0.f);
      }
      *(float4*)&C[(size_t)grow * Nc + gcol] = v;
    }
  }
}

// ------------------------------------------------- attention scalars s,d [N,H]
__global__ __launch_bounds__(256) void k_attn_scalars(const float* __restrict__ h,
                                                      const float* __restrict__ a_src,
                                                      const float* __restrict__ a_dst,
                                                      float* __restrict__ s,
                                                      float* __restrict__ d,
                                                      int H) {
  int wid = threadIdx.x >> 6, lane = threadIdx.x & 63;
  int p = blockIdx.x * 4 + wid;  // (n,h) pair index
  if (p >= NN * H) return;
  int n = p / H, hh = p % H;
  const float* hp = h + (size_t)n * H * 128 + hh * 128;
  float vs = hp[lane] * a_src[hh * 128 + lane] + hp[lane + 64] * a_src[hh * 128 + lane + 64];
  float vd = hp[lane] * a_dst[hh * 128 + lane] + hp[lane + 64] * a_dst[hh * 128 + lane + 64];
#pragma unroll
  for (int o = 32; o > 0; o >>= 1) {
    vs += __shfl_xor(vs, o);
    vd += __shfl_xor(vd, o);
  }
  if (lane == 0) { s[p] = vs; d[p] = vd; }
}

// ------------------------------------- per-(node,head) segment max + denom
__global__ __launch_bounds__(256) void k_node_softmax(const float* __restrict__ s,
                                                      const float* __restrict__ dv,
                                                      const int* __restrict__ row_ptr,
                                                      const int* __restrict__ col_src,
                                                      float* __restrict__ m_out,
                                                      float* __restrict__ den_out,
                                                      int H) {
  int wid = threadIdx.x >> 6, lane = threadIdx.x & 63;
  int p = blockIdx.x * 4 + wid;
  if (p >= NN * H) return;
  int n = p / H, hh = p % H;
  int beg = row_ptr[n], end = row_ptr[n + 1];
  float dn = dv[p];
  float m = -INFINITY;
  for (int e = beg + lane; e < end; e += 64) {
    float ev = s[col_src[e] * H + hh] + dn;
    ev = ev > 0.f ? ev : 0.2f * ev;
    m = fmaxf(m, ev);
  }
#pragma unroll
  for (int o = 32; o > 0; o >>= 1) m = fmaxf(m, __shfl_xor(m, o));
  float ds = 0.f;
  for (int e = beg + lane; e < end; e += 64) {
    float ev = s[col_src[e] * H + hh] + dn;
    ev = ev > 0.f ? ev : 0.2f * ev;
    ds += __expf(ev - m);
  }
#pragma unroll
  for (int o = 32; o > 0; o >>= 1) ds += __shfl_xor(ds, o);
  if (lane == 0) { m_out[p] = m; den_out[p] = ds; }
}

// ----------------------------------------- per-edge alpha written to CSR slot
__global__ __launch_bounds__(256) void k_alpha(const int* __restrict__ edge,
                                               const float* __restrict__ s,
                                               const float* __restrict__ dv,
                                               const float* __restrict__ m,
                                               const float* __restrict__ den,
                                               const int* __restrict__ eid2pos,
                                               float* __restrict__ alpha,
                                               int H) {
  int e = blockIdx.x * 256 + threadIdx.x;
  if (e >= ET) return;
  int ss, dd;
  if (e < EE) { ss = edge[e]; dd = edge[EE + e]; }
  else        { ss = dd = e - EE; }
  int pos = eid2pos[e];
  for (int h = 0; h < H; ++h) {
    float ev = s[ss * H + h] + dv[dd * H + h];
    ev = ev > 0.f ? ev : 0.2f * ev;
    alpha[pos * H + h] = __expf(ev - m[dd * H + h]) / den[dd * H + h];
  }
}

// ------------------------------------------------ weighted gather aggregation
__global__ void k_aggregate(const float* __restrict__ h,
                            const float* __restrict__ alpha,
                            const int* __restrict__ row_ptr,
                            const int* __restrict__ col_src,
                            const float* __restrict__ bias,
                            float* __restrict__ out,
                            int H) {
  int n = blockIdx.x;
  int j = threadIdx.x;         // blockDim = H*128
  int OUTW = H << 7;
  int hh = j >> 7;
  int beg = row_ptr[n], end = row_ptr[n + 1];
  float acc = 0.f;
  for (int e = beg; e < end; ++e) {
    int src = col_src[e];
    acc += alpha[e * H + hh] * h[(size_t)src * OUTW + j];
  }
  out[(size_t)n * OUTW + j] = acc + bias[j];
}

// ---------------------------------------------------------------- launch
extern "C" void kernel_launch(void* const* d_in, const int* in_sizes, int n_in,
                              void* d_out, int out_size, void* d_ws, size_t ws_size,
                              hipStream_t stream) {
  const float* x     = (const float*)d_in[0];
  const int*   edge  = (const int*)d_in[1];
  const float* fc_w  = (const float*)d_in[2];
  const float* fc_b  = (const float*)d_in[3];
  const float* W1    = (const float*)d_in[4];
  const float* asrc1 = (const float*)d_in[5];
  const float* adst1 = (const float*)d_in[6];
  const float* b1    = (const float*)d_in[7];
  const float* Wm    = (const float*)d_in[8];
  const float* asrcm = (const float*)d_in[9];
  const float* adstm = (const float*)d_in[10];
  const float* bm    = (const float*)d_in[11];
  const float* W6    = (const float*)d_in[12];
  const float* asrc6 = (const float*)d_in[13];
  const float* adst6 = (const float*)d_in[14];
  const float* b6    = (const float*)d_in[15];

  char* w = (char*)d_ws;
  size_t off = 0;
  auto carve = [&](size_t bytes) -> char* {
    char* p = w + off;
    off = (off + bytes + 255) & ~(size_t)255;
    return p;
  };
  float* featA  = (float*)carve((size_t)NN * 256 * 4);
  float* featB  = (float*)carve((size_t)NN * 256 * 4);
  float* sbuf   = (float*)carve((size_t)NN * 2 * 4);
  float* dbuf   = (float*)carve((size_t)NN * 2 * 4);
  float* mbuf   = (float*)carve((size_t)NN * 2 * 4);
  float* denom  = (float*)carve((size_t)NN * 2 * 4);
  float* alpha  = (float*)carve((size_t)ET * 2 * 4);
  int* counts   = (int*)carve((size_t)NN * 4);
  int* row_ptr  = (int*)carve((size_t)(NN + 1) * 4);
  int* cursor   = (int*)carve((size_t)NN * 4);
  int* col_src  = (int*)carve((size_t)ET * 4);
  int* eid2pos  = (int*)carve((size_t)ET * 4);
  (void)ws_size;

  // CSR build (graph identical for all 6 layers)
  hipMemsetAsync(counts, 0, (size_t)NN * 4, stream);
  int eb = (ET + 255) / 256;
  k_count<<<eb, 256, 0, stream>>>(edge, counts);
  k_scan<<<1, 1024, 0, stream>>>(counts, row_ptr, cursor);
  k_fill<<<eb, 256, 0, stream>>>(edge, cursor, col_src, eid2pos);

  dim3 g1((NN + 127) / 128, 1), g2((NN + 127) / 128, 2);

  auto gat = [&](const float* in, int K, const float* W, const float* a_s,
                 const float* a_d, const float* bias, float* hbuf, float* outp, int H) {
    k_gemm<<<(H == 2 ? g2 : g1), 256, 0, stream>>>(in, W, hbuf, NN, K, H * 128, nullptr, 0);
    int pairs = NN * H;
    k_attn_scalars<<<(pairs + 3) / 4, 256, 0, stream>>>(hbuf, a_s, a_d, sbuf, dbuf, H);
    k_node_softmax<<<(pairs + 3) / 4, 256, 0, stream>>>(sbuf, dbuf, row_ptr, col_src, mbuf, denom, H);
    k_alpha<<<eb, 256, 0, stream>>>(edge, sbuf, dbuf, mbuf, denom, eid2pos, alpha, H);
    k_aggregate<<<NN, H * 128, 0, stream>>>(hbuf, alpha, row_ptr, col_src, bias, outp, H);
  };

  // fc: relu(x @ fc_w + fc_b) -> featA [N,128]
  k_gemm<<<g1, 256, 0, stream>>>(x, fc_w, featA, NN, 64, 128, fc_b, 1);

  // layer 1: 128 -> 2x128 concat
  gat(featA, 128, W1, asrc1, adst1, b1, featB, featA, 2);

  // middle layers: 256 -> 2x128 concat
  for (int i = 0; i < 4; ++i) {
    gat(featA, 256, Wm + (size_t)i * 256 * 256, asrcm + (size_t)i * 2 * 128,
        adstm + (size_t)i * 2 * 128, bm + (size_t)i * 256, featB, featA, 2);
  }

  // layer 6: 256 -> 1x128
  gat(featA, 256, W6, asrc6, adst6, b6, featB, (float*)d_out, 1);
}

// Round 2
// 1472.370 us; speedup vs baseline: 1.5097x; 1.5097x over previous
//
#include <hip/hip_runtime.h>
#include <cstdint>
#include <cstddef>

#define NN 50000
#define EE 800000
#define ET 850000   // EE + NN self loops

typedef unsigned short ushort_t;
using frag_ab = __attribute__((ext_vector_type(8))) short;   // 8 bf16
using f32x4   = __attribute__((ext_vector_type(4))) float;

__device__ inline ushort_t f2b(float x) {
  union { float f; unsigned int u; } c; c.f = x;
  unsigned int u = c.u;
  u += 0x7fffu + ((u >> 16) & 1u);   // round-to-nearest-even
  return (ushort_t)(u >> 16);
}

// ---------------------------------------------------------------- CSR build
__global__ __launch_bounds__(256) void k_count(const int* __restrict__ edge,
                                               int* __restrict__ counts) {
  int e = blockIdx.x * 256 + threadIdx.x;
  if (e >= ET) return;
  int dd = (e < EE) ? edge[EE + e] : (e - EE);
  atomicAdd(&counts[dd], 1);
}

__global__ __launch_bounds__(1024) void k_scan(const int* __restrict__ counts,
                                               int* __restrict__ row_ptr,
                                               int* __restrict__ cursor) {
  __shared__ int tmp[1024];
  const int CH = (NN + 1023) / 1024;
  int tid = threadIdx.x;
  int base = tid * CH;
  int sum = 0;
  for (int i = 0; i < CH; ++i) {
    int idx = base + i;
    if (idx < NN) sum += counts[idx];
  }
  tmp[tid] = sum;
  __syncthreads();
  for (int o = 1; o < 1024; o <<= 1) {
    int v = (tid >= o) ? tmp[tid - o] : 0;
    __syncthreads();
    tmp[tid] += v;
    __syncthreads();
  }
  int off = tmp[tid] - sum;
  for (int i = 0; i < CH; ++i) {
    int idx = base + i;
    if (idx < NN) {
      row_ptr[idx] = off;
      cursor[idx] = off;
      off += counts[idx];
    }
  }
  if (tid == 0) row_ptr[NN] = ET;
}

__global__ __launch_bounds__(256) void k_fill(const int* __restrict__ edge,
                                              int* __restrict__ cursor,
                                              int* __restrict__ col_src,
                                              int* __restrict__ eid2pos) {
  int e = blockIdx.x * 256 + threadIdx.x;
  if (e >= ET) return;
  int ss, dd;
  if (e < EE) { ss = edge[e]; dd = edge[EE + e]; }
  else        { ss = dd = e - EE; }
  int pos = atomicAdd(&cursor[dd], 1);
  col_src[pos] = ss;
  eid2pos[e] = pos;
}

// ---------------------------------------------------- weight prep (bf16, [n][k])
__global__ __launch_bounds__(256) void k_prep_w(const float* __restrict__ fc_w,
                                                const float* __restrict__ W1,
                                                const float* __restrict__ Wm,
                                                const float* __restrict__ W6,
                                                ushort_t* __restrict__ fcWt,
                                                ushort_t* __restrict__ W1t,
                                                ushort_t* __restrict__ Wmt,
                                                ushort_t* __restrict__ W6t) {
  int i = blockIdx.x * 256 + threadIdx.x;
  if (i < 128 * 64) { int n = i >> 6, k = i & 63; fcWt[i] = f2b(fc_w[k * 128 + n]); return; }
  i -= 128 * 64;
  if (i < 256 * 128) { int n = i >> 7, k = i & 127; W1t[i] = f2b(W1[k * 256 + n]); return; }
  i -= 256 * 128;
  if (i < 4 * 256 * 256) {
    int l = i >> 16, r2 = i & 65535, n = r2 >> 8, k = r2 & 255;
    Wmt[i] = f2b(Wm[(size_t)l * 65536 + k * 256 + n]); return;
  }
  i -= 4 * 256 * 256;
  if (i < 128 * 256) { int n = i >> 8, k = i & 255; W6t[i] = f2b(W6[k * 128 + n]); return; }
}

// ---------------------------------------------------------------- MFMA GEMM
// C[M,Nc] = A[M,K] @ Bt[Nc,K]^T, bf16 inputs, f32 accumulate.
// LDS rows padded to 40 bf16 (80B) -> >=2-way-free bank access on ds_read_b128.
template<int ABF16, int OUTBF, int RELU>
__global__ __launch_bounds__(256) void k_mfma_gemm(const void* __restrict__ A,
                                                   const ushort_t* __restrict__ Bt,
                                                   void* __restrict__ C,
                                                   int M, int K, int Nc,
                                                   const float* __restrict__ bias) {
  __shared__ ushort_t As[128 * 40];
  __shared__ ushort_t Bs[128 * 40];
  int row0 = blockIdx.x * 128;
  int col0 = blockIdx.y * 128;
  int t = threadIdx.x;
  int lane = t & 63, w = t >> 6;
  int wr = w >> 1, wc = w & 1;
  int r = lane & 15, kg = lane >> 4;

  f32x4 acc[4][4];
#pragma unroll
  for (int m = 0; m < 4; ++m)
#pragma unroll
    for (int n = 0; n < 4; ++n) acc[m][n] = (f32x4){0.f, 0.f, 0.f, 0.f};

  for (int k0 = 0; k0 < K; k0 += 32) {
    __syncthreads();
    if (ABF16) {
#pragma unroll
      for (int rep = 0; rep < 2; ++rep) {
        int c = t + rep * 256;
        int row = c >> 2, kc = c & 3;
        int grow = row0 + row;
        if (grow < M) {
          uint4 v = *(const uint4*)&((const ushort_t*)A)[(size_t)grow * K + k0 + kc * 8];
          *(uint4*)&As[row * 40 + kc * 8] = v;
        }
      }
    } else {
#pragma unroll
      for (int rep = 0; rep < 4; ++rep) {
        int c = t + rep * 256;
        int row = c >> 3, kc = c & 7;
        int grow = row0 + row;
        if (grow < M) {
          float4 v = *(const float4*)&((const float*)A)[(size_t)grow * K + k0 + kc * 4];
          ushort4 u;
          u.x = f2b(v.x); u.y = f2b(v.y); u.z = f2b(v.z); u.w = f2b(v.w);
          *(ushort4*)&As[row * 40 + kc * 4] = u;
        }
      }
    }
#pragma unroll
    for (int rep = 0; rep < 2; ++rep) {
      int c = t + rep * 256;
      int row = c >> 2, kc = c & 3;
      uint4 v = *(const uint4*)&Bt[(size_t)(col0 + row) * K + k0 + kc * 8];
      *(uint4*)&Bs[row * 40 + kc * 8] = v;
    }
    __syncthreads();

    frag_ab a[4], b[4];
#pragma unroll
    for (int m = 0; m < 4; ++m)
      a[m] = *(const frag_ab*)&As[(wr * 64 + m * 16 + r) * 40 + kg * 8];
#pragma unroll
    for (int n = 0; n < 4; ++n)
      b[n] = *(const frag_ab*)&Bs[(wc * 64 + n * 16 + r) * 40 + kg * 8];
#pragma unroll
    for (int m = 0; m < 4; ++m)
#pragma unroll
      for (int n = 0; n < 4; ++n)
        acc[m][n] = __builtin_amdgcn_mfma_f32_16x16x32_bf16(a[m], b[n], acc[m][n], 0, 0, 0);
  }

#pragma unroll
  for (int m = 0; m < 4; ++m) {
    int gr0 = row0 + wr * 64 + m * 16 + kg * 4;
#pragma unroll
    for (int q = 0; q < 4; ++q) {
      int grow = gr0 + q;
      if (grow >= M) continue;
#pragma unroll
      for (int n = 0; n < 4; ++n) {
        int gcol = col0 + wc * 64 + n * 16 + r;
        float val = acc[m][n][q];
        if (bias) val += bias[gcol];
        if (RELU) val = fmaxf(val, 0.f);
        if (OUTBF) ((ushort_t*)C)[(size_t)grow * Nc + gcol] = f2b(val);
        else       ((float*)C)[(size_t)grow * Nc + gcol] = val;
      }
    }
  }
}

// ------------------------------------------------- attention scalars s,d [N,H]
__global__ __launch_bounds__(256) void k_attn_scalars(const float* __restrict__ h,
                                                      const float* __restrict__ a_src,
                                                      const float* __restrict__ a_dst,
                                                      float* __restrict__ s,
                                                      float* __restrict__ d,
                                                      int H) {
  int wid = threadIdx.x >> 6, lane = threadIdx.x & 63;
  int p = blockIdx.x * 4 + wid;
  if (p >= NN * H) return;
  int n = p / H, hh = p % H;
  const float* hp = h + (size_t)n * H * 128 + hh * 128;
  float vs = hp[lane] * a_src[hh * 128 + lane] + hp[lane + 64] * a_src[hh * 128 + lane + 64];
  float vd = hp[lane] * a_dst[hh * 128 + lane] + hp[lane + 64] * a_dst[hh * 128 + lane + 64];
#pragma unroll
  for (int o = 32; o > 0; o >>= 1) {
    vs += __shfl_xor(vs, o);
    vd += __shfl_xor(vd, o);
  }
  if (lane == 0) { s[p] = vs; d[p] = vd; }
}

// ------------------------------------- per-(node,head) online max + denom
__global__ __launch_bounds__(256) void k_node_softmax(const float* __restrict__ s,
                                                      const float* __restrict__ dv,
                                                      const int* __restrict__ row_ptr,
                                                      const int* __restrict__ col_src,
                                                      float* __restrict__ m_out,
                                                      float* __restrict__ den_out,
                                                      int H) {
  int wid = threadIdx.x >> 6, lane = threadIdx.x & 63;
  int p = blockIdx.x * 4 + wid;
  if (p >= NN * H) return;
  int n = p / H, hh = p % H;
  int beg = row_ptr[n], end = row_ptr[n + 1];
  float dn = dv[p];
  float m = -1e30f, den = 0.f;
  for (int e = beg + lane; e < end; e += 64) {
    float ev = s[col_src[e] * H + hh] + dn;
    ev = ev > 0.f ? ev : 0.2f * ev;
    if (ev > m) { den = den * __expf(m - ev) + 1.f; m = ev; }
    else den += __expf(ev - m);
  }
#pragma unroll
  for (int o = 32; o > 0; o >>= 1) {
    float mo = __shfl_xor(m, o);
    float dno = __shfl_xor(den, o);
    float M2 = fmaxf(m, mo);
    den = den * __expf(m - M2) + dno * __expf(mo - M2);
    m = M2;
  }
  if (lane == 0) { m_out[p] = m; den_out[p] = den; }
}

// ----------------------------------------- per-edge alpha written to CSR slot
__global__ __launch_bounds__(256) void k_alpha(const int* __restrict__ edge,
                                               const float* __restrict__ s,
                                               const float* __restrict__ dv,
                                               const float* __restrict__ m,
                                               const float* __restrict__ den,
                                               const int* __restrict__ eid2pos,
                                               float* __restrict__ alpha,
                                               int H) {
  int e = blockIdx.x * 256 + threadIdx.x;
  if (e >= ET) return;
  int ss, dd;
  if (e < EE) { ss = edge[e]; dd = edge[EE + e]; }
  else        { ss = dd = e - EE; }
  int pos = eid2pos[e];
  for (int h = 0; h < H; ++h) {
    float ev = s[ss * H + h] + dv[dd * H + h];
    ev = ev > 0.f ? ev : 0.2f * ev;
    alpha[pos * H + h] = __expf(ev - m[dd * H + h]) / den[dd * H + h];
  }
}

// ------------------------------------------------ weighted gather aggregation
// unroll-by-4 edge loop: 4 independent row-gathers in flight (was latency-bound)
template<int OUTBF>
__global__ void k_aggregate(const float* __restrict__ h,
                            const float* __restrict__ alpha,
                            const int* __restrict__ row_ptr,
                            const int* __restrict__ col_src,
                            const float* __restrict__ bias,
                            float* __restrict__ outf,
                            ushort_t* __restrict__ outb,
                            int H) {
  int n = blockIdx.x;
  int j = threadIdx.x;         // blockDim = H*128
  int OUTW = H << 7;
  int hh = j >> 7;
  int beg = row_ptr[n], end = row_ptr[n + 1];
  float acc = 0.f;
  int e = beg;
  for (; e + 4 <= end; e += 4) {
    int s0 = col_src[e + 0], s1 = col_src[e + 1];
    int s2 = col_src[e + 2], s3 = col_src[e + 3];
    float a0 = alpha[(e + 0) * H + hh], a1 = alpha[(e + 1) * H + hh];
    float a2 = alpha[(e + 2) * H + hh], a3 = alpha[(e + 3) * H + hh];
    float v0 = h[(size_t)s0 * OUTW + j];
    float v1 = h[(size_t)s1 * OUTW + j];
    float v2 = h[(size_t)s2 * OUTW + j];
    float v3 = h[(size_t)s3 * OUTW + j];
    acc += a0 * v0; acc += a1 * v1; acc += a2 * v2; acc += a3 * v3;
  }
  for (; e < end; ++e)
    acc += alpha[e * H + hh] * h[(size_t)col_src[e] * OUTW + j];
  float rv = acc + bias[j];
  if (OUTBF) outb[(size_t)n * OUTW + j] = f2b(rv);
  else       outf[(size_t)n * OUTW + j] = rv;
}

// ---------------------------------------------------------------- launch
extern "C" void kernel_launch(void* const* d_in, const int* in_sizes, int n_in,
                              void* d_out, int out_size, void* d_ws, size_t ws_size,
                              hipStream_t stream) {
  const float* x     = (const float*)d_in[0];
  const int*   edge  = (const int*)d_in[1];
  const float* fc_w  = (const float*)d_in[2];
  const float* fc_b  = (const float*)d_in[3];
  const float* W1    = (const float*)d_in[4];
  const float* asrc1 = (const float*)d_in[5];
  const float* adst1 = (const float*)d_in[6];
  const float* b1    = (const float*)d_in[7];
  const float* Wm    = (const float*)d_in[8];
  const float* asrcm = (const float*)d_in[9];
  const float* adstm = (const float*)d_in[10];
  const float* bm    = (const float*)d_in[11];
  const float* W6    = (const float*)d_in[12];
  const float* asrc6 = (const float*)d_in[13];
  const float* adst6 = (const float*)d_in[14];
  const float* b6    = (const float*)d_in[15];

  char* w = (char*)d_ws;
  size_t off = 0;
  auto carve = [&](size_t bytes) -> char* {
    char* p = w + off;
    off = (off + bytes + 255) & ~(size_t)255;
    return p;
  };
  ushort_t* feat0 = (ushort_t*)carve((size_t)NN * 256 * 2);
  ushort_t* feat1 = (ushort_t*)carve((size_t)NN * 256 * 2);
  float* hbuf   = (float*)carve((size_t)NN * 256 * 4);
  float* sbuf   = (float*)carve((size_t)NN * 2 * 4);
  float* dbuf   = (float*)carve((size_t)NN * 2 * 4);
  float* mbuf   = (float*)carve((size_t)NN * 2 * 4);
  float* denom  = (float*)carve((size_t)NN * 2 * 4);
  float* alpha  = (float*)carve((size_t)ET * 2 * 4);
  ushort_t* fcWt = (ushort_t*)carve((size_t)128 * 64 * 2);
  ushort_t* W1t  = (ushort_t*)carve((size_t)256 * 128 * 2);
  ushort_t* Wmt  = (ushort_t*)carve((size_t)4 * 256 * 256 * 2);
  ushort_t* W6t  = (ushort_t*)carve((size_t)128 * 256 * 2);
  int* counts   = (int*)carve((size_t)NN * 4);
  int* row_ptr  = (int*)carve((size_t)(NN + 1) * 4);
  int* cursor   = (int*)carve((size_t)NN * 4);
  int* col_src  = (int*)carve((size_t)ET * 4);
  int* eid2pos  = (int*)carve((size_t)ET * 4);
  (void)ws_size;

  // weight prep
  k_prep_w<<<(335872 + 255) / 256, 256, 0, stream>>>(fc_w, W1, Wm, W6, fcWt, W1t, Wmt, W6t);

  // CSR build
  hipMemsetAsync(counts, 0, (size_t)NN * 4, stream);
  int eb = (ET + 255) / 256;
  k_count<<<eb, 256, 0, stream>>>(edge, counts);
  k_scan<<<1, 1024, 0, stream>>>(counts, row_ptr, cursor);
  k_fill<<<eb, 256, 0, stream>>>(edge, cursor, col_src, eid2pos);

  dim3 g1((NN + 127) / 128, 1), g2((NN + 127) / 128, 2);

  auto gat = [&](const ushort_t* in, int K, const ushort_t* Wt, const float* a_s,
                 const float* a_d, const float* bias, float* outf, ushort_t* outb, int H) {
    k_mfma_gemm<1, 0, 0><<<(H == 2 ? g2 : g1), 256, 0, stream>>>(in, Wt, hbuf, NN, K, H * 128, nullptr);
    int pairs = NN * H;
    k_attn_scalars<<<(pairs + 3) / 4, 256, 0, stream>>>(hbuf, a_s, a_d, sbuf, dbuf, H);
    k_node_softmax<<<(pairs + 3) / 4, 256, 0, stream>>>(sbuf, dbuf, row_ptr, col_src, mbuf, denom, H);
    k_alpha<<<eb, 256, 0, stream>>>(edge, sbuf, dbuf, mbuf, denom, eid2pos, alpha, H);
    if (outb)
      k_aggregate<1><<<NN, H * 128, 0, stream>>>(hbuf, alpha, row_ptr, col_src, bias, nullptr, outb, H);
    else
      k_aggregate<0><<<NN, H * 128, 0, stream>>>(hbuf, alpha, row_ptr, col_src, bias, outf, nullptr, H);
  };

  // fc: relu(x @ fc_w + fc_b) -> feat0 bf16 [N,128]
  k_mfma_gemm<0, 1, 1><<<g1, 256, 0, stream>>>(x, fcWt, feat0, NN, 64, 128, fc_b);

  // layer 1: 128 -> 2x128 concat
  gat(feat0, 128, W1t, asrc1, adst1, b1, nullptr, feat1, 2);

  // middle layers: 256 -> 2x128 concat (ping-pong feat1 <-> feat0)
  const ushort_t* cur = feat1;
  ushort_t* nxt = feat0;
  for (int i = 0; i < 4; ++i) {
    gat(cur, 256, Wmt + (size_t)i * 256 * 256, asrcm + (size_t)i * 2 * 128,
        adstm + (size_t)i * 2 * 128, bm + (size_t)i * 256, nullptr, nxt, 2);
    const ushort_t* tmp = cur;
    cur = nxt;
    nxt = (ushort_t*)tmp;
  }

  // layer 6: 256 -> 1x128, f32 out to d_out
  gat(cur, 256, W6t, asrc6, adst6, b6, (float*)d_out, nullptr, 1);
}

// Round 4
// 769.635 us; speedup vs baseline: 2.8882x; 1.9131x over previous
//
#include <hip/hip_runtime.h>
#include <cstdint>
#include <cstddef>

#define NN 50000
#define EE 800000
#define ET 850000   // EE + NN self loops

typedef unsigned short ushort_t;
typedef unsigned int uint_t;
using frag_ab = __attribute__((ext_vector_type(8))) short;   // 8 bf16
using f32x4   = __attribute__((ext_vector_type(4))) float;

__device__ inline ushort_t f2b(float x) {
  union { float f; unsigned int u; } c; c.f = x;
  unsigned int u = c.u;
  u += 0x7fffu + ((u >> 16) & 1u);   // round-to-nearest-even
  return (ushort_t)(u >> 16);
}
__device__ inline float b2f(uint_t u) {
  union { unsigned int u; float f; } c; c.u = u << 16;
  return c.f;
}

// ---------------------------------------------------------------- CSR build
__global__ __launch_bounds__(256) void k_count(const int* __restrict__ edge,
                                               int* __restrict__ counts) {
  int e = blockIdx.x * 256 + threadIdx.x;
  if (e >= ET) return;
  int dd = (e < EE) ? edge[EE + e] : (e - EE);
  atomicAdd(&counts[dd], 1);
}

__global__ __launch_bounds__(1024) void k_scan1(const int* __restrict__ counts,
                                                int* __restrict__ scn,
                                                int* __restrict__ bsum) {
  __shared__ int tmp[1024];
  int tid = threadIdx.x;
  int idx = blockIdx.x * 1024 + tid;
  int v = (idx < NN) ? counts[idx] : 0;
  tmp[tid] = v;
  __syncthreads();
  for (int o = 1; o < 1024; o <<= 1) {
    int u = (tid >= o) ? tmp[tid - o] : 0;
    __syncthreads();
    tmp[tid] += u;
    __syncthreads();
  }
  if (idx < NN) scn[idx] = tmp[tid] - v;       // exclusive within block
  if (tid == 1023) bsum[blockIdx.x] = tmp[1023];
}

__global__ __launch_bounds__(64) void k_scan2(const int* __restrict__ bsum,
                                              int* __restrict__ boff) {
  int l = threadIdx.x;
  const int NB = (NN + 1023) / 1024;           // 49
  int v = (l < NB) ? bsum[l] : 0;
  int own = v;
  for (int o = 1; o < 64; o <<= 1) {
    int u = __shfl_up(v, o);
    if (l >= o) v += u;
  }
  if (l < NB) boff[l] = v - own;               // exclusive block offsets
}

__global__ __launch_bounds__(1024) void k_scan3(const int* __restrict__ scn,
                                                const int* __restrict__ boff,
                                                int* __restrict__ row_ptr,
                                                int* __restrict__ cursor) {
  int idx = blockIdx.x * 1024 + threadIdx.x;
  if (idx < NN) {
    int v = scn[idx] + boff[blockIdx.x];
    row_ptr[idx] = v;
    cursor[idx] = v;
  }
  if (idx == 0) row_ptr[NN] = ET;
}

__global__ __launch_bounds__(256) void k_fill(const int* __restrict__ edge,
                                              int* __restrict__ cursor,
                                              int* __restrict__ col_src) {
  int e = blockIdx.x * 256 + threadIdx.x;
  if (e >= ET) return;
  int ss, dd;
  if (e < EE) { ss = edge[e]; dd = edge[EE + e]; }
  else        { ss = dd = e - EE; }
  int pos = atomicAdd(&cursor[dd], 1);
  col_src[pos] = ss;
}

// ---------------------------------------------------- weight prep (bf16, [n][k])
__global__ __launch_bounds__(256) void k_prep_w(const float* __restrict__ fc_w,
                                                const float* __restrict__ W1,
                                                const float* __restrict__ Wm,
                                                const float* __restrict__ W6,
                                                ushort_t* __restrict__ fcWt,
                                                ushort_t* __restrict__ W1t,
                                                ushort_t* __restrict__ Wmt,
                                                ushort_t* __restrict__ W6t) {
  int i = blockIdx.x * 256 + threadIdx.x;
  if (i < 128 * 64) { int n = i >> 6, k = i & 63; fcWt[i] = f2b(fc_w[k * 128 + n]); return; }
  i -= 128 * 64;
  if (i < 256 * 128) { int n = i >> 7, k = i & 127; W1t[i] = f2b(W1[k * 256 + n]); return; }
  i -= 256 * 128;
  if (i < 4 * 256 * 256) {
    int l = i >> 16, r2 = i & 65535, n = r2 >> 8, k = r2 & 255;
    Wmt[i] = f2b(Wm[(size_t)l * 65536 + k * 256 + n]); return;
  }
  i -= 4 * 256 * 256;
  if (i < 128 * 256) { int n = i >> 8, k = i & 255; W6t[i] = f2b(W6[k * 128 + n]); return; }
}

// ---------------------------------------------------------------- MFMA GEMM
// C[M,Nc] = A[M,K] @ Bt[Nc,K]^T, bf16 in, f32 acc, bf16 out.
// SD=1: also accumulate s[n,h]=h·a_src, d[n,h]=h·a_dst from the f32 accumulator
// via 16-lane shfl reduce + atomicAdd (head == blockIdx.y).
template<int ABF16, int RELU, int SD>
__global__ __launch_bounds__(256) void k_mfma_gemm(const void* __restrict__ A,
                                                   const ushort_t* __restrict__ Bt,
                                                   ushort_t* __restrict__ C,
                                                   int M, int K, int Nc,
                                                   const float* __restrict__ bias,
                                                   const float* __restrict__ a_src,
                                                   const float* __restrict__ a_dst,
                                                   float* __restrict__ sbuf,
                                                   float* __restrict__ dbuf,
                                                   int H) {
  __shared__ ushort_t As[128 * 40];
  __shared__ ushort_t Bs[128 * 40];
  int row0 = blockIdx.x * 128;
  int col0 = blockIdx.y * 128;
  int t = threadIdx.x;
  int lane = t & 63, w = t >> 6;
  int wr = w >> 1, wc = w & 1;
  int r = lane & 15, kg = lane >> 4;

  f32x4 acc[4][4];
#pragma unroll
  for (int m = 0; m < 4; ++m)
#pragma unroll
    for (int n = 0; n < 4; ++n) acc[m][n] = (f32x4){0.f, 0.f, 0.f, 0.f};

  for (int k0 = 0; k0 < K; k0 += 32) {
    __syncthreads();
    if (ABF16) {
#pragma unroll
      for (int rep = 0; rep < 2; ++rep) {
        int c = t + rep * 256;
        int row = c >> 2, kc = c & 3;
        int grow = row0 + row;
        if (grow < M) {
          uint4 v = *(const uint4*)&((const ushort_t*)A)[(size_t)grow * K + k0 + kc * 8];
          *(uint4*)&As[row * 40 + kc * 8] = v;
        }
      }
    } else {
#pragma unroll
      for (int rep = 0; rep < 4; ++rep) {
        int c = t + rep * 256;
        int row = c >> 3, kc = c & 7;
        int grow = row0 + row;
        if (grow < M) {
          float4 v = *(const float4*)&((const float*)A)[(size_t)grow * K + k0 + kc * 4];
          ushort4 u;
          u.x = f2b(v.x); u.y = f2b(v.y); u.z = f2b(v.z); u.w = f2b(v.w);
          *(ushort4*)&As[row * 40 + kc * 4] = u;
        }
      }
    }
#pragma unroll
    for (int rep = 0; rep < 2; ++rep) {
      int c = t + rep * 256;
      int row = c >> 2, kc = c & 3;
      uint4 v = *(const uint4*)&Bt[(size_t)(col0 + row) * K + k0 + kc * 8];
      *(uint4*)&Bs[row * 40 + kc * 8] = v;
    }
    __syncthreads();

    frag_ab a[4], b[4];
#pragma unroll
    for (int m = 0; m < 4; ++m)
      a[m] = *(const frag_ab*)&As[(wr * 64 + m * 16 + r) * 40 + kg * 8];
#pragma unroll
    for (int n = 0; n < 4; ++n)
      b[n] = *(const frag_ab*)&Bs[(wc * 64 + n * 16 + r) * 40 + kg * 8];
#pragma unroll
    for (int m = 0; m < 4; ++m)
#pragma unroll
      for (int n = 0; n < 4; ++n)
        acc[m][n] = __builtin_amdgcn_mfma_f32_16x16x32_bf16(a[m], b[n], acc[m][n], 0, 0, 0);
  }

  int head = blockIdx.y;
  float as_[4], ad_[4];
  if (SD) {
#pragma unroll
    for (int n = 0; n < 4; ++n) {
      int cloc = wc * 64 + n * 16 + r;
      as_[n] = a_src[head * 128 + cloc];
      ad_[n] = a_dst[head * 128 + cloc];
    }
  }

#pragma unroll
  for (int m = 0; m < 4; ++m) {
    int gr0 = row0 + wr * 64 + m * 16 + kg * 4;
#pragma unroll
    for (int q = 0; q < 4; ++q) {
      int grow = gr0 + q;
      if (grow >= M) continue;            // uniform within 16-lane r-group
      float ps = 0.f, pd = 0.f;
#pragma unroll
      for (int n = 0; n < 4; ++n) {
        int gcol = col0 + wc * 64 + n * 16 + r;
        float val = acc[m][n][q];
        if (SD) { ps += val * as_[n]; pd += val * ad_[n]; }
        if (bias) val += bias[gcol];
        if (RELU) val = fmaxf(val, 0.f);
        C[(size_t)grow * Nc + gcol] = f2b(val);
      }
      if (SD) {
#pragma unroll
        for (int o = 1; o < 16; o <<= 1) {
          ps += __shfl_xor(ps, o);
          pd += __shfl_xor(pd, o);
        }
        if (r == 0) {
          atomicAdd(&sbuf[(size_t)grow * H + head], ps);
          atomicAdd(&dbuf[(size_t)grow * H + head], pd);
        }
      }
    }
  }
}

// ------------------------------------- per-node segment max + denom (16-lane group)
template<int H>
__global__ __launch_bounds__(256) void k_softmax(const float* __restrict__ s,
                                                 const float* __restrict__ dv,
                                                 const int* __restrict__ row_ptr,
                                                 const int* __restrict__ col_src,
                                                 float* __restrict__ m_out,
                                                 float* __restrict__ den_out) {
  int node = blockIdx.x * 16 + (threadIdx.x >> 4);
  int l2 = threadIdx.x & 15;
  if (node >= NN) return;
  int beg = row_ptr[node], end = row_ptr[node + 1];
  float dn0, dn1 = 0.f;
  if (H == 2) { float2 dn = ((const float2*)dv)[node]; dn0 = dn.x; dn1 = dn.y; }
  else dn0 = dv[node];
  float m0 = -1e30f, d0 = 0.f, m1 = -1e30f, d1 = 0.f;
  for (int e = beg + l2; e < end; e += 16) {
    int src = col_src[e];
    if (H == 2) {
      float2 sv = ((const float2*)s)[src];
      float e0 = sv.x + dn0; e0 = e0 > 0.f ? e0 : 0.2f * e0;
      if (e0 > m0) { d0 = d0 * __expf(m0 - e0) + 1.f; m0 = e0; } else d0 += __expf(e0 - m0);
      float e1 = sv.y + dn1; e1 = e1 > 0.f ? e1 : 0.2f * e1;
      if (e1 > m1) { d1 = d1 * __expf(m1 - e1) + 1.f; m1 = e1; } else d1 += __expf(e1 - m1);
    } else {
      float e0 = s[src] + dn0; e0 = e0 > 0.f ? e0 : 0.2f * e0;
      if (e0 > m0) { d0 = d0 * __expf(m0 - e0) + 1.f; m0 = e0; } else d0 += __expf(e0 - m0);
    }
  }
#pragma unroll
  for (int o = 1; o < 16; o <<= 1) {
    float mo = __shfl_xor(m0, o), dno = __shfl_xor(d0, o);
    float M2 = fmaxf(m0, mo);
    d0 = d0 * __expf(m0 - M2) + dno * __expf(mo - M2);
    m0 = M2;
    if (H == 2) {
      mo = __shfl_xor(m1, o); dno = __shfl_xor(d1, o);
      M2 = fmaxf(m1, mo);
      d1 = d1 * __expf(m1 - M2) + dno * __expf(mo - M2);
      m1 = M2;
    }
  }
  if (l2 == 0) {
    if (H == 2) {
      ((float2*)m_out)[node] = make_float2(m0, m1);
      ((float2*)den_out)[node] = make_float2(d0, d1);
    } else {
      m_out[node] = m0;
      den_out[node] = d0;
    }
  }
}

// --------------------------- fused alpha + weighted gather (bf16 h, uint loads)
template<int H, int OUTBF>
__global__ void k_aggregate(const ushort_t* __restrict__ h2,
                            const float* __restrict__ s,
                            const float* __restrict__ dv,
                            const float* __restrict__ m,
                            const float* __restrict__ den,
                            const int* __restrict__ row_ptr,
                            const int* __restrict__ col_src,
                            const float* __restrict__ bias,
                            void* __restrict__ out) {
  int n = blockIdx.x;
  int j = threadIdx.x;                 // channel pair index (2 bf16 per thread)
  int hh = j >> 6;
  const int W = H * 64;                // uints per row
  int beg = row_ptr[n], end = row_ptr[n + 1];
  float mh = m[n * H + hh], dnh = dv[n * H + hh], dh = den[n * H + hh];
  const uint_t* hrow = (const uint_t*)h2;
  float a0 = 0.f, a1 = 0.f;
  int e = beg;
  for (; e + 4 <= end; e += 4) {
    int s0 = col_src[e + 0], s1 = col_src[e + 1];
    int s2 = col_src[e + 2], s3 = col_src[e + 3];
    float x0 = s[s0 * H + hh], x1 = s[s1 * H + hh];
    float x2 = s[s2 * H + hh], x3 = s[s3 * H + hh];
    uint_t v0 = hrow[(size_t)s0 * W + j], v1 = hrow[(size_t)s1 * W + j];
    uint_t v2 = hrow[(size_t)s2 * W + j], v3 = hrow[(size_t)s3 * W + j];
    x0 += dnh; x0 = x0 > 0.f ? x0 : 0.2f * x0; float p0 = __expf(x0 - mh);
    x1 += dnh; x1 = x1 > 0.f ? x1 : 0.2f * x1; float p1 = __expf(x1 - mh);
    x2 += dnh; x2 = x2 > 0.f ? x2 : 0.2f * x2; float p2 = __expf(x2 - mh);
    x3 += dnh; x3 = x3 > 0.f ? x3 : 0.2f * x3; float p3 = __expf(x3 - mh);
    a0 += p0 * b2f(v0 & 0xffffu); a1 += p0 * b2f(v0 >> 16);
    a0 += p1 * b2f(v1 & 0xffffu); a1 += p1 * b2f(v1 >> 16);
    a0 += p2 * b2f(v2 & 0xffffu); a1 += p2 * b2f(v2 >> 16);
    a0 += p3 * b2f(v3 & 0xffffu); a1 += p3 * b2f(v3 >> 16);
  }
  for (; e < end; ++e) {
    int s0 = col_src[e];
    float x0 = s[s0 * H + hh];
    uint_t v0 = hrow[(size_t)s0 * W + j];
    x0 += dnh; x0 = x0 > 0.f ? x0 : 0.2f * x0; float p0 = __expf(x0 - mh);
    a0 += p0 * b2f(v0 & 0xffffu); a1 += p0 * b2f(v0 >> 16);
  }
  float2 bb = ((const float2*)bias)[j];
  float o0 = a0 / dh + bb.x;
  float o1 = a1 / dh + bb.y;
  if (OUTBF) {
    ((uint_t*)out)[(size_t)n * W + j] = (uint_t)f2b(o0) | ((uint_t)f2b(o1) << 16);
  } else {
    ((float2*)out)[(size_t)n * W + j] = make_float2(o0, o1);
  }
}

// ---------------------------------------------------------------- launch
extern "C" void kernel_launch(void* const* d_in, const int* in_sizes, int n_in,
                              void* d_out, int out_size, void* d_ws, size_t ws_size,
                              hipStream_t stream) {
  const float* x     = (const float*)d_in[0];
  const int*   edge  = (const int*)d_in[1];
  const float* fc_w  = (const float*)d_in[2];
  const float* fc_b  = (const float*)d_in[3];
  const float* W1    = (const float*)d_in[4];
  const float* asrc1 = (const float*)d_in[5];
  const float* adst1 = (const float*)d_in[6];
  const float* b1    = (const float*)d_in[7];
  const float* Wm    = (const float*)d_in[8];
  const float* asrcm = (const float*)d_in[9];
  const float* adstm = (const float*)d_in[10];
  const float* bm    = (const float*)d_in[11];
  const float* W6    = (const float*)d_in[12];
  const float* asrc6 = (const float*)d_in[13];
  const float* adst6 = (const float*)d_in[14];
  const float* b6    = (const float*)d_in[15];

  char* w = (char*)d_ws;
  size_t off = 0;
  auto carve = [&](size_t bytes) -> char* {
    char* p = w + off;
    off = (off + bytes + 255) & ~(size_t)255;
    return p;
  };
  ushort_t* feat0 = (ushort_t*)carve((size_t)NN * 256 * 2);
  ushort_t* feat1 = (ushort_t*)carve((size_t)NN * 256 * 2);
  ushort_t* hbuf  = (ushort_t*)carve((size_t)NN * 256 * 2);
  float* sbuf   = (float*)carve((size_t)NN * 2 * 4);
  float* dbuf   = (float*)carve((size_t)NN * 2 * 4);
  float* mbuf   = (float*)carve((size_t)NN * 2 * 4);
  float* denb   = (float*)carve((size_t)NN * 2 * 4);
  ushort_t* fcWt = (ushort_t*)carve((size_t)128 * 64 * 2);
  ushort_t* W1t  = (ushort_t*)carve((size_t)256 * 128 * 2);
  ushort_t* Wmt  = (ushort_t*)carve((size_t)4 * 256 * 256 * 2);
  ushort_t* W6t  = (ushort_t*)carve((size_t)128 * 256 * 2);
  int* counts   = (int*)carve((size_t)NN * 4);
  int* row_ptr  = (int*)carve((size_t)(NN + 1) * 4);
  int* cursor   = (int*)carve((size_t)NN * 4);
  int* col_src  = (int*)carve((size_t)ET * 4);
  int* scn      = (int*)carve((size_t)NN * 4);
  int* bsum     = (int*)carve((size_t)64 * 4);
  int* boff     = (int*)carve((size_t)64 * 4);
  (void)ws_size;

  // weight prep
  k_prep_w<<<(335872 + 255) / 256, 256, 0, stream>>>(fc_w, W1, Wm, W6, fcWt, W1t, Wmt, W6t);

  // CSR build
  hipMemsetAsync(counts, 0, (size_t)NN * 4, stream);
  int eb = (ET + 255) / 256;
  const int NB = (NN + 1023) / 1024;   // 49
  k_count<<<eb, 256, 0, stream>>>(edge, counts);
  k_scan1<<<NB, 1024, 0, stream>>>(counts, scn, bsum);
  k_scan2<<<1, 64, 0, stream>>>(bsum, boff);
  k_scan3<<<NB, 1024, 0, stream>>>(scn, boff, row_ptr, cursor);
  k_fill<<<eb, 256, 0, stream>>>(edge, cursor, col_src);

  dim3 g1((NN + 127) / 128, 1), g2((NN + 127) / 128, 2);

  auto gat = [&](const ushort_t* in, int K, const ushort_t* Wt, const float* a_s,
                 const float* a_d, const float* bias, void* outp, int H, int outbf) {
    hipMemsetAsync(sbuf, 0, (size_t)NN * H * 4, stream);
    hipMemsetAsync(dbuf, 0, (size_t)NN * H * 4, stream);
    k_mfma_gemm<1, 0, 1><<<(H == 2 ? g2 : g1), 256, 0, stream>>>(
        in, Wt, hbuf, NN, K, H * 128, nullptr, a_s, a_d, sbuf, dbuf, H);
    if (H == 2) {
      k_softmax<2><<<(NN + 15) / 16, 256, 0, stream>>>(sbuf, dbuf, row_ptr, col_src, mbuf, denb);
      if (outbf)
        k_aggregate<2, 1><<<NN, 128, 0, stream>>>(hbuf, sbuf, dbuf, mbuf, denb, row_ptr, col_src, bias, outp);
      else
        k_aggregate<2, 0><<<NN, 128, 0, stream>>>(hbuf, sbuf, dbuf, mbuf, denb, row_ptr, col_src, bias, outp);
    } else {
      k_softmax<1><<<(NN + 15) / 16, 256, 0, stream>>>(sbuf, dbuf, row_ptr, col_src, mbuf, denb);
      if (outbf)
        k_aggregate<1, 1><<<NN, 64, 0, stream>>>(hbuf, sbuf, dbuf, mbuf, denb, row_ptr, col_src, bias, outp);
      else
        k_aggregate<1, 0><<<NN, 64, 0, stream>>>(hbuf, sbuf, dbuf, mbuf, denb, row_ptr, col_src, bias, outp);
    }
  };

  // fc: relu(x @ fc_w + fc_b) -> feat0 bf16 [N,128]
  k_mfma_gemm<0, 1, 0><<<g1, 256, 0, stream>>>(x, fcWt, feat0, NN, 64, 128, fc_b,
                                               nullptr, nullptr, nullptr, nullptr, 1);

  // layer 1: 128 -> 2x128 concat
  gat(feat0, 128, W1t, asrc1, adst1, b1, feat1, 2, 1);

  // middle layers: 256 -> 2x128 concat (ping-pong)
  const ushort_t* cur = feat1;
  ushort_t* nxt = feat0;
  for (int i = 0; i < 4; ++i) {
    gat(cur, 256, Wmt + (size_t)i * 256 * 256, asrcm + (size_t)i * 2 * 128,
        adstm + (size_t)i * 2 * 128, bm + (size_t)i * 256, nxt, 2, 1);
    const ushort_t* tmp = cur;
    cur = nxt;
    nxt = (ushort_t*)tmp;
  }

  // layer 6: 256 -> 1x128, f32 out to d_out
  gat(cur, 256, W6t, asrc6, adst6, b6, d_out, 1, 0);
}

// Round 5
// 659.109 us; speedup vs baseline: 3.3726x; 1.1677x over previous
//
#include <hip/hip_runtime.h>
#include <cstdint>
#include <cstddef>

#define NN 50000
#define EE 800000
#define ET 850000   // EE + NN self loops

typedef unsigned short ushort_t;
typedef unsigned int uint_t;
using frag_ab = __attribute__((ext_vector_type(8))) short;   // 8 bf16
using f32x4   = __attribute__((ext_vector_type(4))) float;

__device__ inline ushort_t f2b(float x) {
  union { float f; unsigned int u; } c; c.f = x;
  unsigned int u = c.u;
  u += 0x7fffu + ((u >> 16) & 1u);   // round-to-nearest-even
  return (ushort_t)(u >> 16);
}
__device__ inline float b2f(uint_t u) {
  union { unsigned int u; float f; } c; c.u = u << 16;
  return c.f;
}

// ---------------------------------------------------------------- CSR build
__global__ __launch_bounds__(256) void k_count(const int* __restrict__ edge,
                                               int* __restrict__ counts) {
  int e = blockIdx.x * 256 + threadIdx.x;
  if (e >= ET) return;
  int dd = (e < EE) ? edge[EE + e] : (e - EE);
  atomicAdd(&counts[dd], 1);
}

__global__ __launch_bounds__(1024) void k_scan1(const int* __restrict__ counts,
                                                int* __restrict__ scn,
                                                int* __restrict__ bsum) {
  __shared__ int tmp[1024];
  int tid = threadIdx.x;
  int idx = blockIdx.x * 1024 + tid;
  int v = (idx < NN) ? counts[idx] : 0;
  tmp[tid] = v;
  __syncthreads();
  for (int o = 1; o < 1024; o <<= 1) {
    int u = (tid >= o) ? tmp[tid - o] : 0;
    __syncthreads();
    tmp[tid] += u;
    __syncthreads();
  }
  if (idx < NN) scn[idx] = tmp[tid] - v;       // exclusive within block
  if (tid == 1023) bsum[blockIdx.x] = tmp[1023];
}

__global__ __launch_bounds__(64) void k_scan2(const int* __restrict__ bsum,
                                              int* __restrict__ boff) {
  int l = threadIdx.x;
  const int NB = (NN + 1023) / 1024;           // 49
  int v = (l < NB) ? bsum[l] : 0;
  int own = v;
  for (int o = 1; o < 64; o <<= 1) {
    int u = __shfl_up(v, o);
    if (l >= o) v += u;
  }
  if (l < NB) boff[l] = v - own;               // exclusive block offsets
}

__global__ __launch_bounds__(1024) void k_scan3(const int* __restrict__ scn,
                                                const int* __restrict__ boff,
                                                int* __restrict__ row_ptr,
                                                int* __restrict__ cursor) {
  int idx = blockIdx.x * 1024 + threadIdx.x;
  if (idx < NN) {
    int v = scn[idx] + boff[blockIdx.x];
    row_ptr[idx] = v;
    cursor[idx] = v;
  }
  if (idx == 0) row_ptr[NN] = ET;
}

__global__ __launch_bounds__(256) void k_fill(const int* __restrict__ edge,
                                              int* __restrict__ cursor,
                                              int* __restrict__ col_src) {
  int e = blockIdx.x * 256 + threadIdx.x;
  if (e >= ET) return;
  int ss, dd;
  if (e < EE) { ss = edge[e]; dd = edge[EE + e]; }
  else        { ss = dd = e - EE; }
  int pos = atomicAdd(&cursor[dd], 1);
  col_src[pos] = ss;
}

// ---------------------------------------------------- weight prep (bf16, [n][k])
__global__ __launch_bounds__(256) void k_prep_w(const float* __restrict__ fc_w,
                                                const float* __restrict__ W1,
                                                const float* __restrict__ Wm,
                                                const float* __restrict__ W6,
                                                ushort_t* __restrict__ fcWt,
                                                ushort_t* __restrict__ W1t,
                                                ushort_t* __restrict__ Wmt,
                                                ushort_t* __restrict__ W6t) {
  int i = blockIdx.x * 256 + threadIdx.x;
  if (i < 128 * 64) { int n = i >> 6, k = i & 63; fcWt[i] = f2b(fc_w[k * 128 + n]); return; }
  i -= 128 * 64;
  if (i < 256 * 128) { int n = i >> 7, k = i & 127; W1t[i] = f2b(W1[k * 256 + n]); return; }
  i -= 256 * 128;
  if (i < 4 * 256 * 256) {
    int l = i >> 16, r2 = i & 65535, n = r2 >> 8, k = r2 & 255;
    Wmt[i] = f2b(Wm[(size_t)l * 65536 + k * 256 + n]); return;
  }
  i -= 4 * 256 * 256;
  if (i < 128 * 256) { int n = i >> 8, k = i & 255; W6t[i] = f2b(W6[k * 128 + n]); return; }
}

// ---------------------------------------------------------------- MFMA GEMM
// C[M,Nc] = A[M,K] @ Bt[Nc,K]^T, bf16 in, f32 acc, bf16 out.
// SD=1: also s[n,h]=h·a_src, d[n,h]=h·a_dst via 16-lane shfl reduce + LDS
// cross-wave reduce + plain store (blockIdx.y == head owns all its columns).
template<int ABF16, int RELU, int SD>
__global__ __launch_bounds__(256) void k_mfma_gemm(const void* __restrict__ A,
                                                   const ushort_t* __restrict__ Bt,
                                                   ushort_t* __restrict__ C,
                                                   int M, int K, int Nc,
                                                   const float* __restrict__ bias,
                                                   const float* __restrict__ a_src,
                                                   const float* __restrict__ a_dst,
                                                   float* __restrict__ sbuf,
                                                   float* __restrict__ dbuf,
                                                   int H) {
  __shared__ ushort_t As[128 * 40];
  __shared__ ushort_t Bs[128 * 40];
  __shared__ float sdred[128][2][2];   // [row][wc][{s,d}]
  int row0 = blockIdx.x * 128;
  int col0 = blockIdx.y * 128;
  int t = threadIdx.x;
  int lane = t & 63, w = t >> 6;
  int wr = w >> 1, wc = w & 1;
  int r = lane & 15, kg = lane >> 4;

  f32x4 acc[4][4];
#pragma unroll
  for (int m = 0; m < 4; ++m)
#pragma unroll
    for (int n = 0; n < 4; ++n) acc[m][n] = (f32x4){0.f, 0.f, 0.f, 0.f};

  for (int k0 = 0; k0 < K; k0 += 32) {
    __syncthreads();
    if (ABF16) {
#pragma unroll
      for (int rep = 0; rep < 2; ++rep) {
        int c = t + rep * 256;
        int row = c >> 2, kc = c & 3;
        int grow = row0 + row;
        if (grow < M) {
          uint4 v = *(const uint4*)&((const ushort_t*)A)[(size_t)grow * K + k0 + kc * 8];
          *(uint4*)&As[row * 40 + kc * 8] = v;
        }
      }
    } else {
#pragma unroll
      for (int rep = 0; rep < 4; ++rep) {
        int c = t + rep * 256;
        int row = c >> 3, kc = c & 7;
        int grow = row0 + row;
        if (grow < M) {
          float4 v = *(const float4*)&((const float*)A)[(size_t)grow * K + k0 + kc * 4];
          ushort4 u;
          u.x = f2b(v.x); u.y = f2b(v.y); u.z = f2b(v.z); u.w = f2b(v.w);
          *(ushort4*)&As[row * 40 + kc * 4] = u;
        }
      }
    }
#pragma unroll
    for (int rep = 0; rep < 2; ++rep) {
      int c = t + rep * 256;
      int row = c >> 2, kc = c & 3;
      uint4 v = *(const uint4*)&Bt[(size_t)(col0 + row) * K + k0 + kc * 8];
      *(uint4*)&Bs[row * 40 + kc * 8] = v;
    }
    __syncthreads();

    frag_ab a[4], b[4];
#pragma unroll
    for (int m = 0; m < 4; ++m)
      a[m] = *(const frag_ab*)&As[(wr * 64 + m * 16 + r) * 40 + kg * 8];
#pragma unroll
    for (int n = 0; n < 4; ++n)
      b[n] = *(const frag_ab*)&Bs[(wc * 64 + n * 16 + r) * 40 + kg * 8];
#pragma unroll
    for (int m = 0; m < 4; ++m)
#pragma unroll
      for (int n = 0; n < 4; ++n)
        acc[m][n] = __builtin_amdgcn_mfma_f32_16x16x32_bf16(a[m], b[n], acc[m][n], 0, 0, 0);
  }

  int head = blockIdx.y;
  float as_[4], ad_[4];
  if (SD) {
#pragma unroll
    for (int n = 0; n < 4; ++n) {
      int cloc = wc * 64 + n * 16 + r;
      as_[n] = a_src[head * 128 + cloc];
      ad_[n] = a_dst[head * 128 + cloc];
    }
  }

#pragma unroll
  for (int m = 0; m < 4; ++m) {
    int gr0 = row0 + wr * 64 + m * 16 + kg * 4;
#pragma unroll
    for (int q = 0; q < 4; ++q) {
      int grow = gr0 + q;
      float ps = 0.f, pd = 0.f;
      if (grow < M) {
#pragma unroll
        for (int n = 0; n < 4; ++n) {
          int gcol = col0 + wc * 64 + n * 16 + r;
          float val = acc[m][n][q];
          if (SD) { ps += val * as_[n]; pd += val * ad_[n]; }
          if (bias) val += bias[gcol];
          if (RELU) val = fmaxf(val, 0.f);
          C[(size_t)grow * Nc + gcol] = f2b(val);
        }
      }
      if (SD) {
#pragma unroll
        for (int o = 1; o < 16; o <<= 1) {
          ps += __shfl_xor(ps, o);
          pd += __shfl_xor(pd, o);
        }
        int row_loc = wr * 64 + m * 16 + kg * 4 + q;
        if (r == 0) { sdred[row_loc][wc][0] = ps; sdred[row_loc][wc][1] = pd; }
      }
    }
  }
  if (SD) {
    __syncthreads();
    int row = t >> 1, which = t & 1;
    int grow = row0 + row;
    if (grow < M) {
      float v = sdred[row][0][which] + sdred[row][1][which];
      float* dst = which ? dbuf : sbuf;
      dst[(size_t)grow * H + head] = v;
    }
  }
}

// ----------------------- fused per-node softmax + alpha + weighted gather
// wave-per-node; pass A: online m/den (lane-strided edges, shfl reduce);
// pass B: alpha computed once per (edge,head) in lanes, shfl-broadcast,
// uint2 (H=2) / uint (H=1) gather of bf16 h rows.
template<int H, int OUTBF>
__global__ __launch_bounds__(256) void k_agg(const ushort_t* __restrict__ h2,
                                             const float* __restrict__ s,
                                             const float* __restrict__ dv,
                                             const int* __restrict__ row_ptr,
                                             const int* __restrict__ col_src,
                                             const float* __restrict__ bias,
                                             void* __restrict__ out) {
  int wid = threadIdx.x >> 6, l = threadIdx.x & 63;
  int n = blockIdx.x * 4 + wid;
  if (n >= NN) return;
  int beg = row_ptr[n], end = row_ptr[n + 1];
  float dn0, dn1 = 0.f;
  if (H == 2) { float2 tdn = ((const float2*)dv)[n]; dn0 = tdn.x; dn1 = tdn.y; }
  else dn0 = dv[n];

  // ---- pass A: online max + denom
  float m0 = -1e30f, d0 = 0.f, m1 = -1e30f, d1 = 0.f;
  for (int e = beg + l; e < end; e += 64) {
    int src = col_src[e];
    if (H == 2) {
      float2 sv = ((const float2*)s)[src];
      float x0 = sv.x + dn0; x0 = x0 > 0.f ? x0 : 0.2f * x0;
      if (x0 > m0) { d0 = d0 * __expf(m0 - x0) + 1.f; m0 = x0; } else d0 += __expf(x0 - m0);
      float x1 = sv.y + dn1; x1 = x1 > 0.f ? x1 : 0.2f * x1;
      if (x1 > m1) { d1 = d1 * __expf(m1 - x1) + 1.f; m1 = x1; } else d1 += __expf(x1 - m1);
    } else {
      float x0 = s[src] + dn0; x0 = x0 > 0.f ? x0 : 0.2f * x0;
      if (x0 > m0) { d0 = d0 * __expf(m0 - x0) + 1.f; m0 = x0; } else d0 += __expf(x0 - m0);
    }
  }
#pragma unroll
  for (int o = 1; o < 64; o <<= 1) {
    float mo = __shfl_xor(m0, o), dno = __shfl_xor(d0, o);
    float M2 = fmaxf(m0, mo);
    d0 = d0 * __expf(m0 - M2) + dno * __expf(mo - M2);
    m0 = M2;
    if (H == 2) {
      mo = __shfl_xor(m1, o); dno = __shfl_xor(d1, o);
      M2 = fmaxf(m1, mo);
      d1 = d1 * __expf(m1 - M2) + dno * __expf(mo - M2);
      m1 = M2;
    }
  }

  // ---- pass B
  if (H == 2) {
    const uint2* hrow = (const uint2*)h2;
    int hh = l >> 5;                     // head for channels 4l..4l+3
    float a0 = 0.f, a1 = 0.f, a2 = 0.f, a3 = 0.f;
    for (int c = beg; c < end; c += 32) {
      int cnt = min(32, end - c);
      float alpv = 0.f; int srcv = 0;
      if (l < 2 * cnt) {
        int e = c + (l >> 1), hi = l & 1;
        srcv = col_src[e];
        float x = s[srcv * 2 + hi] + (hi ? dn1 : dn0);
        x = x > 0.f ? x : 0.2f * x;
        alpv = __expf(x - (hi ? m1 : m0));
      }
      int e = 0;
      for (; e + 4 <= cnt; e += 4) {
        float p0 = __shfl(alpv, 2 * e + hh);     int s0 = __shfl(srcv, 2 * e);
        float p1 = __shfl(alpv, 2 * e + 2 + hh); int s1 = __shfl(srcv, 2 * e + 2);
        float p2 = __shfl(alpv, 2 * e + 4 + hh); int s2 = __shfl(srcv, 2 * e + 4);
        float p3 = __shfl(alpv, 2 * e + 6 + hh); int s3 = __shfl(srcv, 2 * e + 6);
        uint2 v0 = hrow[(size_t)s0 * 64 + l];
        uint2 v1 = hrow[(size_t)s1 * 64 + l];
        uint2 v2 = hrow[(size_t)s2 * 64 + l];
        uint2 v3 = hrow[(size_t)s3 * 64 + l];
        a0 += p0 * b2f(v0.x & 0xffffu); a1 += p0 * b2f(v0.x >> 16);
        a2 += p0 * b2f(v0.y & 0xffffu); a3 += p0 * b2f(v0.y >> 16);
        a0 += p1 * b2f(v1.x & 0xffffu); a1 += p1 * b2f(v1.x >> 16);
        a2 += p1 * b2f(v1.y & 0xffffu); a3 += p1 * b2f(v1.y >> 16);
        a0 += p2 * b2f(v2.x & 0xffffu); a1 += p2 * b2f(v2.x >> 16);
        a2 += p2 * b2f(v2.y & 0xffffu); a3 += p2 * b2f(v2.y >> 16);
        a0 += p3 * b2f(v3.x & 0xffffu); a1 += p3 * b2f(v3.x >> 16);
        a2 += p3 * b2f(v3.y & 0xffffu); a3 += p3 * b2f(v3.y >> 16);
      }
      for (; e < cnt; ++e) {
        float p = __shfl(alpv, 2 * e + hh); int sc = __shfl(srcv, 2 * e);
        uint2 v = hrow[(size_t)sc * 64 + l];
        a0 += p * b2f(v.x & 0xffffu); a1 += p * b2f(v.x >> 16);
        a2 += p * b2f(v.y & 0xffffu); a3 += p * b2f(v.y >> 16);
      }
    }
    float dh = hh ? d1 : d0;
    float4 bb = ((const float4*)bias)[l];
    float o0 = a0 / dh + bb.x, o1 = a1 / dh + bb.y;
    float o2 = a2 / dh + bb.z, o3 = a3 / dh + bb.w;
    if (OUTBF) {
      uint2 ov;
      ov.x = (uint_t)f2b(o0) | ((uint_t)f2b(o1) << 16);
      ov.y = (uint_t)f2b(o2) | ((uint_t)f2b(o3) << 16);
      ((uint2*)out)[(size_t)n * 64 + l] = ov;
    } else {
      ((float4*)out)[(size_t)n * 64 + l] = make_float4(o0, o1, o2, o3);
    }
  } else {
    const uint_t* hrow = (const uint_t*)h2;
    float a0 = 0.f, a1 = 0.f;
    for (int c = beg; c < end; c += 64) {
      int cnt = min(64, end - c);
      float alpv = 0.f; int srcv = 0;
      if (l < cnt) {
        srcv = col_src[c + l];
        float x = s[srcv] + dn0;
        x = x > 0.f ? x : 0.2f * x;
        alpv = __expf(x - m0);
      }
      int e = 0;
      for (; e + 4 <= cnt; e += 4) {
        float p0 = __shfl(alpv, e);     int s0 = __shfl(srcv, e);
        float p1 = __shfl(alpv, e + 1); int s1 = __shfl(srcv, e + 1);
        float p2 = __shfl(alpv, e + 2); int s2 = __shfl(srcv, e + 2);
        float p3 = __shfl(alpv, e + 3); int s3 = __shfl(srcv, e + 3);
        uint_t v0 = hrow[(size_t)s0 * 64 + l];
        uint_t v1 = hrow[(size_t)s1 * 64 + l];
        uint_t v2 = hrow[(size_t)s2 * 64 + l];
        uint_t v3 = hrow[(size_t)s3 * 64 + l];
        a0 += p0 * b2f(v0 & 0xffffu); a1 += p0 * b2f(v0 >> 16);
        a0 += p1 * b2f(v1 & 0xffffu); a1 += p1 * b2f(v1 >> 16);
        a0 += p2 * b2f(v2 & 0xffffu); a1 += p2 * b2f(v2 >> 16);
        a0 += p3 * b2f(v3 & 0xffffu); a1 += p3 * b2f(v3 >> 16);
      }
      for (; e < cnt; ++e) {
        float p = __shfl(alpv, e); int sc = __shfl(srcv, e);
        uint_t v = hrow[(size_t)sc * 64 + l];
        a0 += p * b2f(v & 0xffffu); a1 += p * b2f(v >> 16);
      }
    }
    float2 bb = ((const float2*)bias)[l];
    float o0 = a0 / d0 + bb.x, o1 = a1 / d0 + bb.y;
    if (OUTBF) {
      ((uint_t*)out)[(size_t)n * 64 + l] = (uint_t)f2b(o0) | ((uint_t)f2b(o1) << 16);
    } else {
      ((float2*)out)[(size_t)n * 64 + l] = make_float2(o0, o1);
    }
  }
}

// ---------------------------------------------------------------- launch
extern "C" void kernel_launch(void* const* d_in, const int* in_sizes, int n_in,
                              void* d_out, int out_size, void* d_ws, size_t ws_size,
                              hipStream_t stream) {
  const float* x     = (const float*)d_in[0];
  const int*   edge  = (const int*)d_in[1];
  const float* fc_w  = (const float*)d_in[2];
  const float* fc_b  = (const float*)d_in[3];
  const float* W1    = (const float*)d_in[4];
  const float* asrc1 = (const float*)d_in[5];
  const float* adst1 = (const float*)d_in[6];
  const float* b1    = (const float*)d_in[7];
  const float* Wm    = (const float*)d_in[8];
  const float* asrcm = (const float*)d_in[9];
  const float* adstm = (const float*)d_in[10];
  const float* bm    = (const float*)d_in[11];
  const float* W6    = (const float*)d_in[12];
  const float* asrc6 = (const float*)d_in[13];
  const float* adst6 = (const float*)d_in[14];
  const float* b6    = (const float*)d_in[15];

  char* w = (char*)d_ws;
  size_t off = 0;
  auto carve = [&](size_t bytes) -> char* {
    char* p = w + off;
    off = (off + bytes + 255) & ~(size_t)255;
    return p;
  };
  ushort_t* feat0 = (ushort_t*)carve((size_t)NN * 256 * 2);
  ushort_t* feat1 = (ushort_t*)carve((size_t)NN * 256 * 2);
  ushort_t* hbuf  = (ushort_t*)carve((size_t)NN * 256 * 2);
  float* sbuf   = (float*)carve((size_t)NN * 2 * 4);
  float* dbuf   = (float*)carve((size_t)NN * 2 * 4);
  ushort_t* fcWt = (ushort_t*)carve((size_t)128 * 64 * 2);
  ushort_t* W1t  = (ushort_t*)carve((size_t)256 * 128 * 2);
  ushort_t* Wmt  = (ushort_t*)carve((size_t)4 * 256 * 256 * 2);
  ushort_t* W6t  = (ushort_t*)carve((size_t)128 * 256 * 2);
  int* counts   = (int*)carve((size_t)NN * 4);
  int* row_ptr  = (int*)carve((size_t)(NN + 1) * 4);
  int* cursor   = (int*)carve((size_t)NN * 4);
  int* col_src  = (int*)carve((size_t)ET * 4);
  int* scn      = (int*)carve((size_t)NN * 4);
  int* bsum     = (int*)carve((size_t)64 * 4);
  int* boff     = (int*)carve((size_t)64 * 4);
  (void)ws_size;

  // weight prep
  k_prep_w<<<(335872 + 255) / 256, 256, 0, stream>>>(fc_w, W1, Wm, W6, fcWt, W1t, Wmt, W6t);

  // CSR build
  hipMemsetAsync(counts, 0, (size_t)NN * 4, stream);
  int eb = (ET + 255) / 256;
  const int NB = (NN + 1023) / 1024;   // 49
  k_count<<<eb, 256, 0, stream>>>(edge, counts);
  k_scan1<<<NB, 1024, 0, stream>>>(counts, scn, bsum);
  k_scan2<<<1, 64, 0, stream>>>(bsum, boff);
  k_scan3<<<NB, 1024, 0, stream>>>(scn, boff, row_ptr, cursor);
  k_fill<<<eb, 256, 0, stream>>>(edge, cursor, col_src);

  dim3 g1((NN + 127) / 128, 1), g2((NN + 127) / 128, 2);
  int ab = (NN + 3) / 4;   // k_agg blocks: 4 wave-nodes per 256-thread block

  auto gat = [&](const ushort_t* in, int K, const ushort_t* Wt, const float* a_s,
                 const float* a_d, const float* bias, void* outp, int H, int outbf) {
    k_mfma_gemm<1, 0, 1><<<(H == 2 ? g2 : g1), 256, 0, stream>>>(
        in, Wt, hbuf, NN, K, H * 128, nullptr, a_s, a_d, sbuf, dbuf, H);
    if (H == 2) {
      if (outbf)
        k_agg<2, 1><<<ab, 256, 0, stream>>>(hbuf, sbuf, dbuf, row_ptr, col_src, bias, outp);
      else
        k_agg<2, 0><<<ab, 256, 0, stream>>>(hbuf, sbuf, dbuf, row_ptr, col_src, bias, outp);
    } else {
      if (outbf)
        k_agg<1, 1><<<ab, 256, 0, stream>>>(hbuf, sbuf, dbuf, row_ptr, col_src, bias, outp);
      else
        k_agg<1, 0><<<ab, 256, 0, stream>>>(hbuf, sbuf, dbuf, row_ptr, col_src, bias, outp);
    }
  };

  // fc: relu(x @ fc_w + fc_b) -> feat0 bf16 [N,128]
  k_mfma_gemm<0, 1, 0><<<g1, 256, 0, stream>>>(x, fcWt, feat0, NN, 64, 128, fc_b,
                                               nullptr, nullptr, nullptr, nullptr, 1);

  // layer 1: 128 -> 2x128 concat
  gat(feat0, 128, W1t, asrc1, adst1, b1, feat1, 2, 1);

  // middle layers: 256 -> 2x128 concat (ping-pong)
  const ushort_t* cur = feat1;
  ushort_t* nxt = feat0;
  for (int i = 0; i < 4; ++i) {
    gat(cur, 256, Wmt + (size_t)i * 256 * 256, asrcm + (size_t)i * 2 * 128,
        adstm + (size_t)i * 2 * 128, bm + (size_t)i * 256, nxt, 2, 1);
    const ushort_t* tmp = cur;
    cur = nxt;
    nxt = (ushort_t*)tmp;
  }

  // layer 6: 256 -> 1x128, f32 out to d_out
  gat(cur, 256, W6t, asrc6, adst6, b6, d_out, 1, 0);
}

// Round 6
// 599.342 us; speedup vs baseline: 3.7089x; 1.0997x over previous
//
#include <hip/hip_runtime.h>
#include <cstdint>
#include <cstddef>

#define NN 50000
#define EE 800000
#define ET 850000   // EE + NN self loops

typedef unsigned short ushort_t;
typedef unsigned int uint_t;
using frag_ab = __attribute__((ext_vector_type(8))) short;   // 8 bf16
using f32x4   = __attribute__((ext_vector_type(4))) float;

__device__ inline ushort_t f2b(float x) {
  union { float f; unsigned int u; } c; c.f = x;
  unsigned int u = c.u;
  u += 0x7fffu + ((u >> 16) & 1u);   // round-to-nearest-even
  return (ushort_t)(u >> 16);
}
__device__ inline float b2f(uint_t u) {
  union { unsigned int u; float f; } c; c.u = u << 16;
  return c.f;
}

// async global->LDS, 16B per lane; LDS dest = wave-uniform base + lane*16
__device__ inline void gload16(const ushort_t* g, ushort_t* l) {
  __builtin_amdgcn_global_load_lds(
      (const __attribute__((address_space(1))) unsigned int*)g,
      (__attribute__((address_space(3))) unsigned int*)l, 16, 0, 0);
}

// ---------------------------------------------------------------- CSR build
__global__ __launch_bounds__(256) void k_count(const int* __restrict__ edge,
                                               int* __restrict__ counts) {
  int e = blockIdx.x * 256 + threadIdx.x;
  if (e >= ET) return;
  int dd = (e < EE) ? edge[EE + e] : (e - EE);
  atomicAdd(&counts[dd], 1);
}

__global__ __launch_bounds__(1024) void k_scan1(const int* __restrict__ counts,
                                                int* __restrict__ scn,
                                                int* __restrict__ bsum) {
  __shared__ int tmp[1024];
  int tid = threadIdx.x;
  int idx = blockIdx.x * 1024 + tid;
  int v = (idx < NN) ? counts[idx] : 0;
  tmp[tid] = v;
  __syncthreads();
  for (int o = 1; o < 1024; o <<= 1) {
    int u = (tid >= o) ? tmp[tid - o] : 0;
    __syncthreads();
    tmp[tid] += u;
    __syncthreads();
  }
  if (idx < NN) scn[idx] = tmp[tid] - v;
  if (tid == 1023) bsum[blockIdx.x] = tmp[1023];
}

__global__ __launch_bounds__(64) void k_scan2(const int* __restrict__ bsum,
                                              int* __restrict__ boff) {
  int l = threadIdx.x;
  const int NB = (NN + 1023) / 1024;           // 49
  int v = (l < NB) ? bsum[l] : 0;
  int own = v;
  for (int o = 1; o < 64; o <<= 1) {
    int u = __shfl_up(v, o);
    if (l >= o) v += u;
  }
  if (l < NB) boff[l] = v - own;
}

__global__ __launch_bounds__(1024) void k_scan3(const int* __restrict__ scn,
                                                const int* __restrict__ boff,
                                                int* __restrict__ row_ptr,
                                                int* __restrict__ cursor) {
  int idx = blockIdx.x * 1024 + threadIdx.x;
  if (idx < NN) {
    int v = scn[idx] + boff[blockIdx.x];
    row_ptr[idx] = v;
    cursor[idx] = v;
  }
  if (idx == 0) row_ptr[NN] = ET;
}

__global__ __launch_bounds__(256) void k_fill(const int* __restrict__ edge,
                                              int* __restrict__ cursor,
                                              int* __restrict__ col_src) {
  int e = blockIdx.x * 256 + threadIdx.x;
  if (e >= ET) return;
  int ss, dd;
  if (e < EE) { ss = edge[e]; dd = edge[EE + e]; }
  else        { ss = dd = e - EE; }
  int pos = atomicAdd(&cursor[dd], 1);
  col_src[pos] = ss;
}

// ---------------------------------------------------- weight prep (bf16, [n][k])
__global__ __launch_bounds__(256) void k_prep_w(const float* __restrict__ fc_w,
                                                const float* __restrict__ W1,
                                                const float* __restrict__ Wm,
                                                const float* __restrict__ W6,
                                                ushort_t* __restrict__ fcWt,
                                                ushort_t* __restrict__ W1t,
                                                ushort_t* __restrict__ Wmt,
                                                ushort_t* __restrict__ W6t) {
  int i = blockIdx.x * 256 + threadIdx.x;
  if (i < 128 * 64) { int n = i >> 6, k = i & 63; fcWt[i] = f2b(fc_w[k * 128 + n]); return; }
  i -= 128 * 64;
  if (i < 256 * 128) { int n = i >> 7, k = i & 127; W1t[i] = f2b(W1[k * 256 + n]); return; }
  i -= 256 * 128;
  if (i < 4 * 256 * 256) {
    int l = i >> 16, r2 = i & 65535, n = r2 >> 8, k = r2 & 255;
    Wmt[i] = f2b(Wm[(size_t)l * 65536 + k * 256 + n]); return;
  }
  i -= 4 * 256 * 256;
  if (i < 128 * 256) { int n = i >> 8, k = i & 255; W6t[i] = f2b(W6[k * 128 + n]); return; }
}

// ---------------------------------------------- fc GEMM (f32 input, old path)
__global__ __launch_bounds__(256) void k_gemm_f32(const float* __restrict__ A,
                                                  const ushort_t* __restrict__ Bt,
                                                  ushort_t* __restrict__ C,
                                                  int M, int K, int Nc,
                                                  const float* __restrict__ bias) {
  __shared__ ushort_t As[128 * 40];
  __shared__ ushort_t Bs[128 * 40];
  int row0 = blockIdx.x * 128;
  int col0 = blockIdx.y * 128;
  int t = threadIdx.x;
  int lane = t & 63, w = t >> 6;
  int wr = w >> 1, wc = w & 1;
  int r = lane & 15, kg = lane >> 4;

  f32x4 acc[4][4];
#pragma unroll
  for (int m = 0; m < 4; ++m)
#pragma unroll
    for (int n = 0; n < 4; ++n) acc[m][n] = (f32x4){0.f, 0.f, 0.f, 0.f};

  for (int k0 = 0; k0 < K; k0 += 32) {
    __syncthreads();
#pragma unroll
    for (int rep = 0; rep < 4; ++rep) {
      int c = t + rep * 256;
      int row = c >> 3, kc = c & 7;
      int grow = row0 + row;
      if (grow < M) {
        float4 v = *(const float4*)&A[(size_t)grow * K + k0 + kc * 4];
        ushort4 u;
        u.x = f2b(v.x); u.y = f2b(v.y); u.z = f2b(v.z); u.w = f2b(v.w);
        *(ushort4*)&As[row * 40 + kc * 4] = u;
      }
    }
#pragma unroll
    for (int rep = 0; rep < 2; ++rep) {
      int c = t + rep * 256;
      int row = c >> 2, kc = c & 3;
      uint4 v = *(const uint4*)&Bt[(size_t)(col0 + row) * K + k0 + kc * 8];
      *(uint4*)&Bs[row * 40 + kc * 8] = v;
    }
    __syncthreads();

    frag_ab a[4], b[4];
#pragma unroll
    for (int m = 0; m < 4; ++m)
      a[m] = *(const frag_ab*)&As[(wr * 64 + m * 16 + r) * 40 + kg * 8];
#pragma unroll
    for (int n = 0; n < 4; ++n)
      b[n] = *(const frag_ab*)&Bs[(wc * 64 + n * 16 + r) * 40 + kg * 8];
#pragma unroll
    for (int m = 0; m < 4; ++m)
#pragma unroll
      for (int n = 0; n < 4; ++n)
        acc[m][n] = __builtin_amdgcn_mfma_f32_16x16x32_bf16(a[m], b[n], acc[m][n], 0, 0, 0);
  }

#pragma unroll
  for (int m = 0; m < 4; ++m) {
    int gr0 = row0 + wr * 64 + m * 16 + kg * 4;
#pragma unroll
    for (int q = 0; q < 4; ++q) {
      int grow = gr0 + q;
      if (grow >= M) continue;
#pragma unroll
      for (int n = 0; n < 4; ++n) {
        int gcol = col0 + wc * 64 + n * 16 + r;
        float val = acc[m][n][q] + bias[gcol];
        val = fmaxf(val, 0.f);
        C[(size_t)grow * Nc + gcol] = f2b(val);
      }
    }
  }
}

// ------------------------------- GAT GEMM: bf16, BK=64, global_load_lds + swizzle
// LDS layout: linear [128 rows][128B]; element (row,kslot8bf16) stored at byte
// row*128 + (kslot*16 ^ ((row&7)<<4)). Staged via inverse-swizzled global src.
__global__ __launch_bounds__(256) void k_gemm64(const ushort_t* __restrict__ A,
                                                const ushort_t* __restrict__ Bt,
                                                ushort_t* __restrict__ C,
                                                int M, int K, int Nc,
                                                const float* __restrict__ a_src,
                                                const float* __restrict__ a_dst,
                                                float* __restrict__ sbuf,
                                                float* __restrict__ dbuf,
                                                int H) {
  __shared__ ushort_t As[128 * 64];
  __shared__ ushort_t Bs[128 * 64];
  __shared__ float sdred[128][2][2];
  int row0 = blockIdx.x * 128;
  int col0 = blockIdx.y * 128;
  int t = threadIdx.x;
  int lane = t & 63, w = t >> 6;
  int wr = w >> 1, wc = w & 1;
  int r = lane & 15, kg = lane >> 4;

  f32x4 acc[4][4];
#pragma unroll
  for (int m = 0; m < 4; ++m)
#pragma unroll
    for (int n = 0; n < 4; ++n) acc[m][n] = (f32x4){0.f, 0.f, 0.f, 0.f};

  for (int k0 = 0; k0 < K; k0 += 64) {
    __syncthreads();
#pragma unroll
    for (int i = 0; i < 4; ++i) {
      int c = w * 4 + i;                 // 1KB chunk id (16 per tile)
      int b = c * 1024 + lane * 16;      // linear LDS byte this lane fills
      int row = b >> 7;
      int ks = ((b >> 4) & 7) ^ (row & 7);   // inverse swizzle on source
      const ushort_t* ga = A + (size_t)(row0 + row) * K + k0 + ks * 8;
      if (row0 + row < M) gload16(ga, &As[c * 512]);
      const ushort_t* gb = Bt + (size_t)(col0 + row) * K + k0 + ks * 8;
      gload16(gb, &Bs[c * 512]);
    }
    __syncthreads();

#pragma unroll
    for (int kk = 0; kk < 2; ++kk) {
      frag_ab af[4], bf[4];
#pragma unroll
      for (int m = 0; m < 4; ++m) {
        int row = wr * 64 + m * 16 + r;
        int byte = row * 128 + ((kk * 64 + kg * 16) ^ ((row & 7) << 4));
        af[m] = *(const frag_ab*)((const char*)As + byte);
      }
#pragma unroll
      for (int n = 0; n < 4; ++n) {
        int row = wc * 64 + n * 16 + r;
        int byte = row * 128 + ((kk * 64 + kg * 16) ^ ((row & 7) << 4));
        bf[n] = *(const frag_ab*)((const char*)Bs + byte);
      }
#pragma unroll
      for (int m = 0; m < 4; ++m)
#pragma unroll
        for (int n = 0; n < 4; ++n)
          acc[m][n] = __builtin_amdgcn_mfma_f32_16x16x32_bf16(af[m], bf[n], acc[m][n], 0, 0, 0);
    }
  }

  int head = blockIdx.y;
  float as_[4], ad_[4];
#pragma unroll
  for (int n = 0; n < 4; ++n) {
    int cloc = wc * 64 + n * 16 + r;
    as_[n] = a_src[head * 128 + cloc];
    ad_[n] = a_dst[head * 128 + cloc];
  }

#pragma unroll
  for (int m = 0; m < 4; ++m) {
    int gr0 = row0 + wr * 64 + m * 16 + kg * 4;
#pragma unroll
    for (int q = 0; q < 4; ++q) {
      int grow = gr0 + q;
      float ps = 0.f, pd = 0.f;
      if (grow < M) {
#pragma unroll
        for (int n = 0; n < 4; ++n) {
          int gcol = col0 + wc * 64 + n * 16 + r;
          float val = acc[m][n][q];
          ps += val * as_[n]; pd += val * ad_[n];
          C[(size_t)grow * Nc + gcol] = f2b(val);
        }
      }
#pragma unroll
      for (int o = 1; o < 16; o <<= 1) {
        ps += __shfl_xor(ps, o);
        pd += __shfl_xor(pd, o);
      }
      int row_loc = wr * 64 + m * 16 + kg * 4 + q;
      if (r == 0) { sdred[row_loc][wc][0] = ps; sdred[row_loc][wc][1] = pd; }
    }
  }
  __syncthreads();
  int row = t >> 1, which = t & 1;
  int grow = row0 + row;
  if (grow < M) {
    float v = sdred[row][0][which] + sdred[row][1][which];
    float* dst = which ? dbuf : sbuf;
    dst[(size_t)grow * H + head] = v;
  }
}

// ------------- fused softmax + alpha + gather, H=2, bf16 out
// pass B: half-wave per edge (lanes 0-31 even edges, 32-63 odd), uint4 gathers.
__global__ __launch_bounds__(256) void k_agg2(const ushort_t* __restrict__ h2,
                                              const float* __restrict__ s,
                                              const float* __restrict__ dv,
                                              const int* __restrict__ row_ptr,
                                              const int* __restrict__ col_src,
                                              const float* __restrict__ bias,
                                              uint4* __restrict__ out) {
  int wid = threadIdx.x >> 6, l = threadIdx.x & 63;
  int n = blockIdx.x * 4 + wid;
  if (n >= NN) return;
  int beg = row_ptr[n], end = row_ptr[n + 1];
  float2 tdn = ((const float2*)dv)[n];
  float dn0 = tdn.x, dn1 = tdn.y;

  // pass A: online max + denom
  float m0 = -1e30f, d0 = 0.f, m1 = -1e30f, d1 = 0.f;
  for (int e = beg + l; e < end; e += 64) {
    int src = col_src[e];
    float2 sv = ((const float2*)s)[src];
    float x0 = sv.x + dn0; x0 = x0 > 0.f ? x0 : 0.2f * x0;
    if (x0 > m0) { d0 = d0 * __expf(m0 - x0) + 1.f; m0 = x0; } else d0 += __expf(x0 - m0);
    float x1 = sv.y + dn1; x1 = x1 > 0.f ? x1 : 0.2f * x1;
    if (x1 > m1) { d1 = d1 * __expf(m1 - x1) + 1.f; m1 = x1; } else d1 += __expf(x1 - m1);
  }
#pragma unroll
  for (int o = 1; o < 64; o <<= 1) {
    float mo = __shfl_xor(m0, o), dno = __shfl_xor(d0, o);
    float M2 = fmaxf(m0, mo);
    d0 = d0 * __expf(m0 - M2) + dno * __expf(mo - M2);
    m0 = M2;
    mo = __shfl_xor(m1, o); dno = __shfl_xor(d1, o);
    M2 = fmaxf(m1, mo);
    d1 = d1 * __expf(m1 - M2) + dno * __expf(mo - M2);
    m1 = M2;
  }

  // pass B
  int hw = l >> 5, lh = l & 31;      // parity half, channel group (8 ch per lane)
  int hd = lh >> 4;                  // head of my channels
  const uint4* hrow = (const uint4*)h2;    // 32 uint4 per row
  float a0 = 0.f, a1 = 0.f, a2 = 0.f, a3 = 0.f;
  float a4 = 0.f, a5 = 0.f, a6 = 0.f, a7 = 0.f;

  for (int c = beg; c < end; c += 32) {
    int cnt = min(32, end - c);
    float alpv = 0.f; int srcv = 0;
    if (l < 2 * cnt) {
      int e = c + (l >> 1), hi = l & 1;
      srcv = col_src[e];
      float x = s[srcv * 2 + hi] + (hi ? dn1 : dn0);
      x = x > 0.f ? x : 0.2f * x;
      alpv = __expf(x - (hi ? m1 : m0));
    }
    int e = 0;
    for (; e + 4 <= cnt + 1; e += 4) {   // pairs (e, e+2); lanes beyond cnt give p=0
      int ep0 = e + hw, ep1 = e + 2 + hw;
      int s0 = __shfl(srcv, 2 * ep0);
      int s1 = __shfl(srcv, 2 * ep1);
      float p0 = __shfl(alpv, 2 * ep0 + hd);
      float p1 = __shfl(alpv, 2 * ep1 + hd);
      if (ep0 >= cnt) p0 = 0.f;
      if (ep1 >= cnt) p1 = 0.f;
      uint4 v0 = hrow[(size_t)s0 * 32 + lh];
      uint4 v1 = hrow[(size_t)s1 * 32 + lh];
      a0 = fmaf(p0, b2f(v0.x & 0xffffu), a0); a1 = fmaf(p0, b2f(v0.x >> 16), a1);
      a2 = fmaf(p0, b2f(v0.y & 0xffffu), a2); a3 = fmaf(p0, b2f(v0.y >> 16), a3);
      a4 = fmaf(p0, b2f(v0.z & 0xffffu), a4); a5 = fmaf(p0, b2f(v0.z >> 16), a5);
      a6 = fmaf(p0, b2f(v0.w & 0xffffu), a6); a7 = fmaf(p0, b2f(v0.w >> 16), a7);
      a0 = fmaf(p1, b2f(v1.x & 0xffffu), a0); a1 = fmaf(p1, b2f(v1.x >> 16), a1);
      a2 = fmaf(p1, b2f(v1.y & 0xffffu), a2); a3 = fmaf(p1, b2f(v1.y >> 16), a3);
      a4 = fmaf(p1, b2f(v1.z & 0xffffu), a4); a5 = fmaf(p1, b2f(v1.z >> 16), a5);
      a6 = fmaf(p1, b2f(v1.w & 0xffffu), a6); a7 = fmaf(p1, b2f(v1.w >> 16), a7);
    }
    for (; e < cnt; e += 2) {
      int ep = e + hw;
      int s0 = __shfl(srcv, 2 * ep);
      float p = __shfl(alpv, 2 * ep + hd);
      if (ep >= cnt) p = 0.f;
      uint4 v = hrow[(size_t)s0 * 32 + lh];
      a0 = fmaf(p, b2f(v.x & 0xffffu), a0); a1 = fmaf(p, b2f(v.x >> 16), a1);
      a2 = fmaf(p, b2f(v.y & 0xffffu), a2); a3 = fmaf(p, b2f(v.y >> 16), a3);
      a4 = fmaf(p, b2f(v.z & 0xffffu), a4); a5 = fmaf(p, b2f(v.z >> 16), a5);
      a6 = fmaf(p, b2f(v.w & 0xffffu), a6); a7 = fmaf(p, b2f(v.w >> 16), a7);
    }
  }
  // cross-parity reduce
  a0 += __shfl_xor(a0, 32); a1 += __shfl_xor(a1, 32);
  a2 += __shfl_xor(a2, 32); a3 += __shfl_xor(a3, 32);
  a4 += __shfl_xor(a4, 32); a5 += __shfl_xor(a5, 32);
  a6 += __shfl_xor(a6, 32); a7 += __shfl_xor(a7, 32);

  if (hw == 0) {
    float dh = hd ? d1 : d0;
    float inv = 1.f / dh;
    float4 b0 = ((const float4*)bias)[2 * lh];
    float4 b1 = ((const float4*)bias)[2 * lh + 1];
    uint4 ov;
    ov.x = (uint_t)f2b(a0 * inv + b0.x) | ((uint_t)f2b(a1 * inv + b0.y) << 16);
    ov.y = (uint_t)f2b(a2 * inv + b0.z) | ((uint_t)f2b(a3 * inv + b0.w) << 16);
    ov.z = (uint_t)f2b(a4 * inv + b1.x) | ((uint_t)f2b(a5 * inv + b1.y) << 16);
    ov.w = (uint_t)f2b(a6 * inv + b1.z) | ((uint_t)f2b(a7 * inv + b1.w) << 16);
    out[(size_t)n * 32 + lh] = ov;
  }
}

// ------------- fused softmax + alpha + gather, H=1, f32 out (last layer)
// pass B: quarter-wave per edge (4 edges in flight), uint4 gathers.
__global__ __launch_bounds__(256) void k_agg1(const ushort_t* __restrict__ h2,
                                              const float* __restrict__ s,
                                              const float* __restrict__ dv,
                                              const int* __restrict__ row_ptr,
                                              const int* __restrict__ col_src,
                                              const float* __restrict__ bias,
                                              float* __restrict__ out) {
  int wid = threadIdx.x >> 6, l = threadIdx.x & 63;
  int n = blockIdx.x * 4 + wid;
  if (n >= NN) return;
  int beg = row_ptr[n], end = row_ptr[n + 1];
  float dn0 = dv[n];

  float m0 = -1e30f, d0 = 0.f;
  for (int e = beg + l; e < end; e += 64) {
    float x0 = s[col_src[e]] + dn0;
    x0 = x0 > 0.f ? x0 : 0.2f * x0;
    if (x0 > m0) { d0 = d0 * __expf(m0 - x0) + 1.f; m0 = x0; } else d0 += __expf(x0 - m0);
  }
#pragma unroll
  for (int o = 1; o < 64; o <<= 1) {
    float mo = __shfl_xor(m0, o), dno = __shfl_xor(d0, o);
    float M2 = fmaxf(m0, mo);
    d0 = d0 * __expf(m0 - M2) + dno * __expf(mo - M2);
    m0 = M2;
  }

  int hw = l >> 4, lh = l & 15;      // edge slot-in-4, channel group
  const uint4* hrow = (const uint4*)h2;   // 16 uint4 per row
  float a0 = 0.f, a1 = 0.f, a2 = 0.f, a3 = 0.f;
  float a4 = 0.f, a5 = 0.f, a6 = 0.f, a7 = 0.f;

  for (int c = beg; c < end; c += 64) {
    int cnt = min(64, end - c);
    float alpv = 0.f; int srcv = 0;
    if (l < cnt) {
      srcv = col_src[c + l];
      float x = s[srcv] + dn0;
      x = x > 0.f ? x : 0.2f * x;
      alpv = __expf(x - m0);
    }
    for (int e = 0; e < cnt; e += 4) {
      int ep = e + hw;
      int s0 = __shfl(srcv, ep);
      float p = __shfl(alpv, ep);
      if (ep >= cnt) p = 0.f;
      uint4 v = hrow[(size_t)s0 * 16 + lh];
      a0 = fmaf(p, b2f(v.x & 0xffffu), a0); a1 = fmaf(p, b2f(v.x >> 16), a1);
      a2 = fmaf(p, b2f(v.y & 0xffffu), a2); a3 = fmaf(p, b2f(v.y >> 16), a3);
      a4 = fmaf(p, b2f(v.z & 0xffffu), a4); a5 = fmaf(p, b2f(v.z >> 16), a5);
      a6 = fmaf(p, b2f(v.w & 0xffffu), a6); a7 = fmaf(p, b2f(v.w >> 16), a7);
    }
  }
#pragma unroll
  for (int o = 16; o < 64; o <<= 1) {
    a0 += __shfl_xor(a0, o); a1 += __shfl_xor(a1, o);
    a2 += __shfl_xor(a2, o); a3 += __shfl_xor(a3, o);
    a4 += __shfl_xor(a4, o); a5 += __shfl_xor(a5, o);
    a6 += __shfl_xor(a6, o); a7 += __shfl_xor(a7, o);
  }
  if (hw == 0) {
    float inv = 1.f / d0;
    float4 b0 = ((const float4*)bias)[2 * lh];
    float4 b1 = ((const float4*)bias)[2 * lh + 1];
    float4 o0 = make_float4(a0 * inv + b0.x, a1 * inv + b0.y, a2 * inv + b0.z, a3 * inv + b0.w);
    float4 o1 = make_float4(a4 * inv + b1.x, a5 * inv + b1.y, a6 * inv + b1.z, a7 * inv + b1.w);
    ((float4*)out)[(size_t)n * 32 + 2 * lh] = o0;
    ((float4*)out)[(size_t)n * 32 + 2 * lh + 1] = o1;
  }
}

// ---------------------------------------------------------------- launch
extern "C" void kernel_launch(void* const* d_in, const int* in_sizes, int n_in,
                              void* d_out, int out_size, void* d_ws, size_t ws_size,
                              hipStream_t stream) {
  const float* x     = (const float*)d_in[0];
  const int*   edge  = (const int*)d_in[1];
  const float* fc_w  = (const float*)d_in[2];
  const float* fc_b  = (const float*)d_in[3];
  const float* W1    = (const float*)d_in[4];
  const float* asrc1 = (const float*)d_in[5];
  const float* adst1 = (const float*)d_in[6];
  const float* b1    = (const float*)d_in[7];
  const float* Wm    = (const float*)d_in[8];
  const float* asrcm = (const float*)d_in[9];
  const float* adstm = (const float*)d_in[10];
  const float* bm    = (const float*)d_in[11];
  const float* W6    = (const float*)d_in[12];
  const float* asrc6 = (const float*)d_in[13];
  const float* adst6 = (const float*)d_in[14];
  const float* b6    = (const float*)d_in[15];

  char* w = (char*)d_ws;
  size_t off = 0;
  auto carve = [&](size_t bytes) -> char* {
    char* p = w + off;
    off = (off + bytes + 255) & ~(size_t)255;
    return p;
  };
  ushort_t* feat0 = (ushort_t*)carve((size_t)NN * 256 * 2);
  ushort_t* feat1 = (ushort_t*)carve((size_t)NN * 256 * 2);
  ushort_t* hbuf  = (ushort_t*)carve((size_t)NN * 256 * 2);
  float* sbuf   = (float*)carve((size_t)NN * 2 * 4);
  float* dbuf   = (float*)carve((size_t)NN * 2 * 4);
  ushort_t* fcWt = (ushort_t*)carve((size_t)128 * 64 * 2);
  ushort_t* W1t  = (ushort_t*)carve((size_t)256 * 128 * 2);
  ushort_t* Wmt  = (ushort_t*)carve((size_t)4 * 256 * 256 * 2);
  ushort_t* W6t  = (ushort_t*)carve((size_t)128 * 256 * 2);
  int* counts   = (int*)carve((size_t)NN * 4);
  int* row_ptr  = (int*)carve((size_t)(NN + 1) * 4);
  int* cursor   = (int*)carve((size_t)NN * 4);
  int* col_src  = (int*)carve((size_t)ET * 4);
  int* scn      = (int*)carve((size_t)NN * 4);
  int* bsum     = (int*)carve((size_t)64 * 4);
  int* boff     = (int*)carve((size_t)64 * 4);
  (void)ws_size;

  // weight prep
  k_prep_w<<<(335872 + 255) / 256, 256, 0, stream>>>(fc_w, W1, Wm, W6, fcWt, W1t, Wmt, W6t);

  // CSR build
  hipMemsetAsync(counts, 0, (size_t)NN * 4, stream);
  int eb = (ET + 255) / 256;
  const int NB = (NN + 1023) / 1024;   // 49
  k_count<<<eb, 256, 0, stream>>>(edge, counts);
  k_scan1<<<NB, 1024, 0, stream>>>(counts, scn, bsum);
  k_scan2<<<1, 64, 0, stream>>>(bsum, boff);
  k_scan3<<<NB, 1024, 0, stream>>>(scn, boff, row_ptr, cursor);
  k_fill<<<eb, 256, 0, stream>>>(edge, cursor, col_src);

  dim3 g1((NN + 127) / 128, 1), g2((NN + 127) / 128, 2);
  int ab = (NN + 3) / 4;

  auto gat = [&](const ushort_t* in, int K, const ushort_t* Wt, const float* a_s,
                 const float* a_d, const float* bias, void* outp, int H) {
    k_gemm64<<<(H == 2 ? g2 : g1), 256, 0, stream>>>(
        in, Wt, hbuf, NN, K, H * 128, a_s, a_d, sbuf, dbuf, H);
    if (H == 2)
      k_agg2<<<ab, 256, 0, stream>>>(hbuf, sbuf, dbuf, row_ptr, col_src, bias, (uint4*)outp);
    else
      k_agg1<<<ab, 256, 0, stream>>>(hbuf, sbuf, dbuf, row_ptr, col_src, bias, (float*)outp);
  };

  // fc: relu(x @ fc_w + fc_b) -> feat0 bf16 [N,128]
  k_gemm_f32<<<g1, 256, 0, stream>>>(x, fcWt, feat0, NN, 64, 128, fc_b);

  // layer 1: 128 -> 2x128 concat
  gat(feat0, 128, W1t, asrc1, adst1, b1, feat1, 2);

  // middle layers: 256 -> 2x128 concat (ping-pong)
  const ushort_t* cur = feat1;
  ushort_t* nxt = feat0;
  for (int i = 0; i < 4; ++i) {
    gat(cur, 256, Wmt + (size_t)i * 256 * 256, asrcm + (size_t)i * 2 * 128,
        adstm + (size_t)i * 2 * 128, bm + (size_t)i * 256, nxt, 2);
    const ushort_t* tmp = cur;
    cur = nxt;
    nxt = (ushort_t*)tmp;
  }

  // layer 6: 256 -> 1x128, f32 out to d_out
  gat(cur, 256, W6t, asrc6, adst6, b6, d_out, 1);
}